// Round 2
// baseline (2605.999 us; speedup 1.0000x reference)
//
#include <hip/hip_runtime.h>
#include <math.h>

#define SCALE_ATTN 0.15811388300841897f

// ---------------- GroupNorm: 32 groups of 10 channels x 4096 ----------------
__global__ __launch_bounds__(256) void groupnorm_kernel(
    const float* __restrict__ x, const float* __restrict__ gs,
    const float* __restrict__ gb, float* __restrict__ out) {
  int g = blockIdx.x, tid = threadIdx.x;
  size_t base = (size_t)g * 40960;
  float sum = 0.f, sq = 0.f;
  for (int e = tid; e < 40960; e += 256) {
    float v = x[base + e];
    sum += v; sq += v * v;
  }
  __shared__ float s1[256], s2[256];
  s1[tid] = sum; s2[tid] = sq; __syncthreads();
  for (int st = 128; st > 0; st >>= 1) {
    if (tid < st) { s1[tid] += s1[tid+st]; s2[tid] += s2[tid+st]; }
    __syncthreads();
  }
  float mu = s1[0] * (1.f/40960.f);
  float var = s2[0] * (1.f/40960.f) - mu*mu;
  float rs = rsqrtf(var + 1e-6f);
  for (int e = tid; e < 40960; e += 256) {
    int c = g*10 + (e >> 12);
    float v = x[base + e];
    out[base + e] = (v - mu) * rs * gs[c] + gb[c];
  }
}

// ---------------- LayerNorm: one wave per row of 320 ----------------
__global__ __launch_bounds__(64) void layernorm_kernel(
    const float* __restrict__ X, const float* __restrict__ s,
    const float* __restrict__ b, float* __restrict__ Y) {
  int row = blockIdx.x, t = threadIdx.x;
  const float* xr = X + (size_t)row*320;
  float v[5], sum = 0.f, sq = 0.f;
  #pragma unroll
  for (int i = 0; i < 5; i++) { v[i] = xr[t + 64*i]; sum += v[i]; sq += v[i]*v[i]; }
  #pragma unroll
  for (int o = 32; o > 0; o >>= 1) { sum += __shfl_down(sum, o); sq += __shfl_down(sq, o); }
  sum = __shfl(sum, 0); sq = __shfl(sq, 0);
  float mu = sum * (1.f/320.f);
  float var = sq * (1.f/320.f) - mu*mu;
  float rs = rsqrtf(var + 1e-5f);
  float* yr = Y + (size_t)row*320;
  #pragma unroll
  for (int i = 0; i < 5; i++) {
    int c = t + 64*i;
    yr[c] = (v[i]-mu)*rs*s[c] + b[c];
  }
}

// ---------------- Tiled GEMM: C[M,N] = A*B (+bias)(+res) ----------------
// A fp32 ([M,K] row-major, or ATRANS: [K,M]); B fp32 [K,N] row-major.
template<bool ATRANS>
__global__ __launch_bounds__(256) void gemm_kernel(
    const float* __restrict__ A, const float* __restrict__ B,
    const float* __restrict__ bias, const float* __restrict__ res,
    float* __restrict__ C, int M, int N, int K) {
  __shared__ float As[16][65];
  __shared__ float Bs[16][65];
  int tid = threadIdx.x;
  int tx = tid & 15, ty = tid >> 4;
  int bm = blockIdx.x * 64, bn = blockIdx.y * 64;
  float acc[4][4] = {};
  for (int k0 = 0; k0 < K; k0 += 16) {
    if (ATRANS) {
      #pragma unroll
      for (int i = 0; i < 4; i++) {
        int e = tid + i*256;
        int m = e & 63, kk = e >> 6;
        int gm = bm + m;
        As[kk][m] = (gm < M) ? A[(size_t)(k0+kk)*M + gm] : 0.f;
      }
    } else {
      #pragma unroll
      for (int i = 0; i < 4; i++) {
        int e = tid + i*256;
        int kk = e & 15, m = e >> 4;
        int gm = bm + m;
        As[kk][m] = (gm < M) ? A[(size_t)gm*K + (k0+kk)] : 0.f;
      }
    }
    #pragma unroll
    for (int i = 0; i < 4; i++) {
      int e = tid + i*256;
      int n = e & 63, kk = e >> 6;
      int gnn = bn + n;
      Bs[kk][n] = (gnn < N) ? B[(size_t)(k0+kk)*N + gnn] : 0.f;
    }
    __syncthreads();
    #pragma unroll
    for (int kk = 0; kk < 16; kk++) {
      float a0[4], b0[4];
      #pragma unroll
      for (int i = 0; i < 4; i++) a0[i] = As[kk][ty*4+i];
      #pragma unroll
      for (int j = 0; j < 4; j++) b0[j] = Bs[kk][tx*4+j];
      #pragma unroll
      for (int i = 0; i < 4; i++)
        #pragma unroll
        for (int j = 0; j < 4; j++) acc[i][j] = fmaf(a0[i], b0[j], acc[i][j]);
    }
    __syncthreads();
  }
  #pragma unroll
  for (int i = 0; i < 4; i++) {
    int m = bm + ty*4 + i;
    if (m >= M) continue;
    #pragma unroll
    for (int j = 0; j < 4; j++) {
      int n = bn + tx*4 + j;
      if (n >= N) continue;
      float vv = acc[i][j];
      if (bias) vv += bias[n];
      if (res)  vv += res[(size_t)m*N + n];
      C[(size_t)m*N + n] = vv;
    }
  }
}

// ---------------- GEGLU GEMM: out[s,j] = (hn@W[:,j]+b[j]) * gelu(hn@W[:,1280+j]+b[1280+j]) ----------------
__global__ __launch_bounds__(256) void geglu_kernel(
    const float* __restrict__ A, const float* __restrict__ B,
    const float* __restrict__ bias, float* __restrict__ C, int K) {
  __shared__ float As[16][65];
  __shared__ float Ba[16][65];
  __shared__ float Bg[16][65];
  int tid = threadIdx.x;
  int tx = tid & 15, ty = tid >> 4;
  int bm = blockIdx.x * 64, bn = blockIdx.y * 64;
  float acca[4][4] = {}, accg[4][4] = {};
  for (int k0 = 0; k0 < K; k0 += 16) {
    #pragma unroll
    for (int i = 0; i < 4; i++) {
      int e = tid + i*256;
      int kk = e & 15, m = e >> 4;
      As[kk][m] = A[(size_t)(bm+m)*K + (k0+kk)];
    }
    #pragma unroll
    for (int i = 0; i < 4; i++) {
      int e = tid + i*256;
      int n = e & 63, kk = e >> 6;
      Ba[kk][n] = B[(size_t)(k0+kk)*2560 + bn + n];
      Bg[kk][n] = B[(size_t)(k0+kk)*2560 + 1280 + bn + n];
    }
    __syncthreads();
    #pragma unroll
    for (int kk = 0; kk < 16; kk++) {
      float a0[4], ba[4], bg[4];
      #pragma unroll
      for (int i = 0; i < 4; i++) a0[i] = As[kk][ty*4+i];
      #pragma unroll
      for (int j = 0; j < 4; j++) { ba[j] = Ba[kk][tx*4+j]; bg[j] = Bg[kk][tx*4+j]; }
      #pragma unroll
      for (int i = 0; i < 4; i++)
        #pragma unroll
        for (int j = 0; j < 4; j++) {
          acca[i][j] = fmaf(a0[i], ba[j], acca[i][j]);
          accg[i][j] = fmaf(a0[i], bg[j], accg[i][j]);
        }
    }
    __syncthreads();
  }
  #pragma unroll
  for (int i = 0; i < 4; i++) {
    int m = bm + ty*4 + i;
    #pragma unroll
    for (int j = 0; j < 4; j++) {
      int n = bn + tx*4 + j;
      float a = acca[i][j] + bias[n];
      float g = accg[i][j] + bias[1280 + n];
      float gl = 0.5f * g * (1.f + erff(g * 0.70710678118654752f));
      C[(size_t)m*1280 + n] = a * gl;
    }
  }
}

// ---------------- proj_out GEMM: out[d,s] = h[s,:]@W[:,d] + b[d] + x[d,s] ----------------
__global__ __launch_bounds__(256) void projout_kernel(
    const float* __restrict__ A, const float* __restrict__ B,
    const float* __restrict__ bias, const float* __restrict__ xin,
    float* __restrict__ out) {
  __shared__ float As[16][65];
  __shared__ float Bs[16][65];
  int tid = threadIdx.x;
  int tx = tid & 15, ty = tid >> 4;
  int bm = blockIdx.x * 64, bn = blockIdx.y * 64;
  float acc[4][4] = {};
  for (int k0 = 0; k0 < 320; k0 += 16) {
    #pragma unroll
    for (int i = 0; i < 4; i++) {
      int e = tid + i*256;
      int kk = e & 15, m = e >> 4;
      As[kk][m] = A[(size_t)(bm+m)*320 + (k0+kk)];
    }
    #pragma unroll
    for (int i = 0; i < 4; i++) {
      int e = tid + i*256;
      int n = e & 63, kk = e >> 6;
      Bs[kk][n] = B[(size_t)(k0+kk)*320 + bn + n];
    }
    __syncthreads();
    #pragma unroll
    for (int kk = 0; kk < 16; kk++) {
      float a0[4], b0[4];
      #pragma unroll
      for (int i = 0; i < 4; i++) a0[i] = As[kk][ty*4+i];
      #pragma unroll
      for (int j = 0; j < 4; j++) b0[j] = Bs[kk][tx*4+j];
      #pragma unroll
      for (int i = 0; i < 4; i++)
        #pragma unroll
        for (int j = 0; j < 4; j++) acc[i][j] = fmaf(a0[i], b0[j], acc[i][j]);
    }
    __syncthreads();
  }
  #pragma unroll
  for (int i = 0; i < 4; i++) {
    int m = bm + ty*4 + i;
    #pragma unroll
    for (int j = 0; j < 4; j++) {
      int n = bn + tx*4 + j;
      out[(size_t)n*4096 + m] = acc[i][j] + bias[n] + xin[(size_t)n*4096 + m];
    }
  }
}

// ---------------- Self-attention: flash-style streaming, TQ=32, TK=64 ----------------
__global__ __launch_bounds__(256) void self_attn_kernel(
    const float* __restrict__ Q, const float* __restrict__ K,
    const float* __restrict__ V, float* __restrict__ O) {
  const int h = blockIdx.y;
  const int q0 = blockIdx.x * 32;
  const int tid = threadIdx.x;
  __shared__ float Qs[32][41];
  __shared__ float Ks[64][41];
  __shared__ float Vs[64][41];
  __shared__ float Ss[32][65];
  __shared__ float Os[32][41];
  __shared__ float mS[32], lS[32], aS[32];
  for (int e = tid; e < 32*40; e += 256) {
    int r = e/40, d = e%40;
    Qs[r][d] = Q[(size_t)(q0+r)*320 + h*40 + d] * SCALE_ATTN;
    Os[r][d] = 0.f;
  }
  if (tid < 32) { mS[tid] = -3.0e38f; lS[tid] = 0.f; }
  __syncthreads();
  for (int kt = 0; kt < 4096; kt += 64) {
    for (int e = tid; e < 64*40; e += 256) {
      int r = e/40, d = e%40;
      Ks[r][d] = K[(size_t)(kt+r)*320 + h*40 + d];
      Vs[r][d] = V[(size_t)(kt+r)*320 + h*40 + d];
    }
    __syncthreads();
    {
      const int c = tid & 63;
      const int r0 = tid >> 6;
      float accS[8] = {0.f,0.f,0.f,0.f,0.f,0.f,0.f,0.f};
      for (int kk = 0; kk < 40; kk++) {
        float kv = Ks[c][kk];
        #pragma unroll
        for (int i = 0; i < 8; i++)
          accS[i] = fmaf(Qs[r0 + 4*i][kk], kv, accS[i]);
      }
      #pragma unroll
      for (int i = 0; i < 8; i++) Ss[r0 + 4*i][c] = accS[i];
    }
    __syncthreads();
    if (tid < 32) {
      float m0 = mS[tid], mx = m0;
      for (int j = 0; j < 64; j++) mx = fmaxf(mx, Ss[tid][j]);
      mS[tid] = mx;
      aS[tid] = __expf(m0 - mx);
    }
    __syncthreads();
    for (int e = tid; e < 32*64; e += 256) {
      int r = e >> 6, c2 = e & 63;
      Ss[r][c2] = __expf(Ss[r][c2] - mS[r]);
    }
    __syncthreads();
    if (tid < 32) {
      float ssum = 0.f;
      for (int j = 0; j < 64; j++) ssum += Ss[tid][j];
      lS[tid] = lS[tid]*aS[tid] + ssum;
    }
    for (int e = tid; e < 32*40; e += 256) {
      int r = e/40, d = e%40;
      float acc = Os[r][d] * aS[r];
      for (int j = 0; j < 64; j++)
        acc = fmaf(Ss[r][j], Vs[j][d], acc);
      Os[r][d] = acc;
    }
    __syncthreads();
  }
  for (int e = tid; e < 32*40; e += 256) {
    int r = e/40, d = e%40;
    O[(size_t)(q0+r)*320 + h*40 + d] = Os[r][d] / lS[r];
  }
}

// ---------------- Cross-attention: one thread per (s, head), 77 keys ----------------
__global__ __launch_bounds__(256) void cross_attn_kernel(
    const float* __restrict__ Q, const float* __restrict__ Kc,
    const float* __restrict__ Vc, float* __restrict__ O) {
  int gid = blockIdx.x * 256 + threadIdx.x;
  int h = gid & 7;
  int s = gid >> 3;
  const float* qp = Q + (size_t)s*320 + h*40;
  float qr[40];
  #pragma unroll
  for (int d = 0; d < 40; d++) qr[d] = qp[d] * SCALE_ATTN;
  float m = -3.0e38f, l = 0.f, acc[40];
  #pragma unroll
  for (int d = 0; d < 40; d++) acc[d] = 0.f;
  for (int t = 0; t < 77; t++) {
    const float* kp = Kc + (size_t)t*320 + h*40;
    float x = 0.f;
    #pragma unroll
    for (int d = 0; d < 40; d++) x = fmaf(qr[d], kp[d], x);
    float mn = fmaxf(m, x);
    float al = __expf(m - mn);
    float p = __expf(x - mn);
    m = mn;
    l = l*al + p;
    const float* vp = Vc + (size_t)t*320 + h*40;
    #pragma unroll
    for (int d = 0; d < 40; d++) acc[d] = acc[d]*al + p*vp[d];
  }
  float inv = 1.f/l;
  float* op = O + (size_t)s*320 + h*40;
  #pragma unroll
  for (int d = 0; d < 40; d++) op[d] = acc[d]*inv;
}

extern "C" void kernel_launch(void* const* d_in, const int* in_sizes, int n_in,
                              void* d_out, int out_size, void* d_ws, size_t ws_size,
                              hipStream_t stream) {
  const float* x        = (const float*)d_in[0];
  const float* ctx      = (const float*)d_in[1];
  const float* gn_s     = (const float*)d_in[2];
  const float* gn_b     = (const float*)d_in[3];
  const float* w_pin    = (const float*)d_in[4];
  const float* b_pin    = (const float*)d_in[5];
  const float* ln1_s    = (const float*)d_in[6];
  const float* ln1_b    = (const float*)d_in[7];
  const float* wq1      = (const float*)d_in[8];
  const float* wk1      = (const float*)d_in[9];
  const float* wv1      = (const float*)d_in[10];
  const float* wo1      = (const float*)d_in[11];
  const float* bo1      = (const float*)d_in[12];
  const float* ln2_s    = (const float*)d_in[13];
  const float* ln2_b    = (const float*)d_in[14];
  const float* wq2      = (const float*)d_in[15];
  const float* wk2      = (const float*)d_in[16];
  const float* wv2      = (const float*)d_in[17];
  const float* wo2      = (const float*)d_in[18];
  const float* bo2      = (const float*)d_in[19];
  const float* ln3_s    = (const float*)d_in[20];
  const float* ln3_b    = (const float*)d_in[21];
  const float* w_ff1    = (const float*)d_in[22];
  const float* b_ff1    = (const float*)d_in[23];
  const float* w_ff2    = (const float*)d_in[24];
  const float* b_ff2    = (const float*)d_in[25];
  const float* w_pout   = (const float*)d_in[26];
  const float* b_pout   = (const float*)d_in[27];
  float* out = (float*)d_out;

  // Aliased workspace: 6 x HB floats = 31.5 MB total.
  float* ws = (float*)d_ws;
  const size_t HB = 4096u*320u;   // 1310720
  float* h    = ws + 0*HB;        // B0: persistent residual stream
  float* hn   = ws + 1*HB;        // B1: LN output
  float* q    = ws + 2*HB;        // B2
  float* k    = ws + 3*HB;        // B3 (also gn before q/k live; kc/vc in cross phase)
  float* v    = ws + 4*HB;        // B4
  float* ao   = ws + 5*HB;        // B5
  float* gn   = k;                // gn dead before k is written
  float* gg   = q;                // GEGLU out overlays B2..B5 (4096*1280)
  float* kc   = k;                // cross K: 77*320 (k dead after self-attn)
  float* vc   = k + 77*320;       // cross V: 77*320

  dim3 g64x5(64, 5), blk(256);

  // GroupNorm -> gn [320,4096]
  hipLaunchKernelGGL(groupnorm_kernel, dim3(32), blk, 0, stream, x, gn_s, gn_b, gn);
  // proj_in: h[s,d] = sum_c gn[c,s]*W[c,d] + b
  hipLaunchKernelGGL((gemm_kernel<true>), g64x5, blk, 0, stream, gn, w_pin, b_pin, (const float*)nullptr, h, 4096, 320, 320);
  // LN1
  hipLaunchKernelGGL(layernorm_kernel, dim3(4096), dim3(64), 0, stream, h, ln1_s, ln1_b, hn);
  // Q,K,V
  hipLaunchKernelGGL((gemm_kernel<false>), g64x5, blk, 0, stream, hn, wq1, (const float*)nullptr, (const float*)nullptr, q, 4096, 320, 320);
  hipLaunchKernelGGL((gemm_kernel<false>), g64x5, blk, 0, stream, hn, wk1, (const float*)nullptr, (const float*)nullptr, k, 4096, 320, 320);
  hipLaunchKernelGGL((gemm_kernel<false>), g64x5, blk, 0, stream, hn, wv1, (const float*)nullptr, (const float*)nullptr, v, 4096, 320, 320);
  // self-attention
  hipLaunchKernelGGL(self_attn_kernel, dim3(128, 8), blk, 0, stream, q, k, v, ao);
  // out proj + residual (in-place h)
  hipLaunchKernelGGL((gemm_kernel<false>), g64x5, blk, 0, stream, ao, wo1, bo1, h, h, 4096, 320, 320);
  // LN2
  hipLaunchKernelGGL(layernorm_kernel, dim3(4096), dim3(64), 0, stream, h, ln2_s, ln2_b, hn);
  // cross Q ; context K,V (ctx fp32 [77,768])
  hipLaunchKernelGGL((gemm_kernel<false>), g64x5, blk, 0, stream, hn, wq2, (const float*)nullptr, (const float*)nullptr, q, 4096, 320, 320);
  hipLaunchKernelGGL((gemm_kernel<false>), dim3(2, 5), blk, 0, stream, ctx, wk2, (const float*)nullptr, (const float*)nullptr, kc, 77, 320, 768);
  hipLaunchKernelGGL((gemm_kernel<false>), dim3(2, 5), blk, 0, stream, ctx, wv2, (const float*)nullptr, (const float*)nullptr, vc, 77, 320, 768);
  // cross-attention
  hipLaunchKernelGGL(cross_attn_kernel, dim3(128), blk, 0, stream, q, kc, vc, ao);
  // out proj + residual
  hipLaunchKernelGGL((gemm_kernel<false>), g64x5, blk, 0, stream, ao, wo2, bo2, h, h, 4096, 320, 320);
  // LN3
  hipLaunchKernelGGL(layernorm_kernel, dim3(4096), dim3(64), 0, stream, h, ln3_s, ln3_b, hn);
  // GEGLU ff1
  hipLaunchKernelGGL(geglu_kernel, dim3(64, 20), blk, 0, stream, hn, w_ff1, b_ff1, gg, 320);
  // ff2 + residual
  hipLaunchKernelGGL((gemm_kernel<false>), g64x5, blk, 0, stream, gg, w_ff2, b_ff2, h, h, 4096, 320, 1280);
  // proj_out + x residual -> out [320, 4096]
  hipLaunchKernelGGL(projout_kernel, g64x5, blk, 0, stream, h, w_pout, b_pout, x, out);
}

// Round 3
// 1394.559 us; speedup vs baseline: 1.8687x; 1.8687x over previous
//
#include <hip/hip_runtime.h>
#include <math.h>

#define SCALE_ATTN 0.15811388300841897f

typedef __attribute__((ext_vector_type(8))) short short8v;
typedef __attribute__((ext_vector_type(4))) float float4v;

__device__ __forceinline__ unsigned short f2bf(float x) {
  unsigned u = __float_as_uint(x);
  unsigned r = (u + 0x7FFFu + ((u >> 16) & 1u)) >> 16;
  return (unsigned short)r;
}
__device__ __forceinline__ unsigned pack2(float a, float b) {
  return (unsigned)f2bf(a) | ((unsigned)f2bf(b) << 16);
}

// ---------------- GroupNorm: 32 groups of 10 channels x 4096 ----------------
__global__ __launch_bounds__(256) void groupnorm_kernel(
    const float* __restrict__ x, const float* __restrict__ gs,
    const float* __restrict__ gb, float* __restrict__ out) {
  int g = blockIdx.x, tid = threadIdx.x;
  size_t base = (size_t)g * 40960;
  float sum = 0.f, sq = 0.f;
  for (int e = tid; e < 40960; e += 256) {
    float v = x[base + e];
    sum += v; sq += v * v;
  }
  __shared__ float s1[256], s2[256];
  s1[tid] = sum; s2[tid] = sq; __syncthreads();
  for (int st = 128; st > 0; st >>= 1) {
    if (tid < st) { s1[tid] += s1[tid+st]; s2[tid] += s2[tid+st]; }
    __syncthreads();
  }
  float mu = s1[0] * (1.f/40960.f);
  float var = s2[0] * (1.f/40960.f) - mu*mu;
  float rs = rsqrtf(var + 1e-6f);
  for (int e = tid; e < 40960; e += 256) {
    int c = g*10 + (e >> 12);
    float v = x[base + e];
    out[base + e] = (v - mu) * rs * gs[c] + gb[c];
  }
}

// ---------------- LayerNorm: one wave per row of 320 ----------------
__global__ __launch_bounds__(64) void layernorm_kernel(
    const float* __restrict__ X, const float* __restrict__ s,
    const float* __restrict__ b, float* __restrict__ Y) {
  int row = blockIdx.x, t = threadIdx.x;
  const float* xr = X + (size_t)row*320;
  float v[5], sum = 0.f, sq = 0.f;
  #pragma unroll
  for (int i = 0; i < 5; i++) { v[i] = xr[t + 64*i]; sum += v[i]; sq += v[i]*v[i]; }
  #pragma unroll
  for (int o = 32; o > 0; o >>= 1) { sum += __shfl_down(sum, o); sq += __shfl_down(sq, o); }
  sum = __shfl(sum, 0); sq = __shfl(sq, 0);
  float mu = sum * (1.f/320.f);
  float var = sq * (1.f/320.f) - mu*mu;
  float rs = rsqrtf(var + 1e-5f);
  float* yr = Y + (size_t)row*320;
  #pragma unroll
  for (int i = 0; i < 5; i++) {
    int c = t + 64*i;
    yr[c] = (v[i]-mu)*rs*s[c] + b[c];
  }
}

// ---------------- Tiled GEMM: C[M,N] = A*B (+bias)(+res) ----------------
template<bool ATRANS>
__global__ __launch_bounds__(256) void gemm_kernel(
    const float* __restrict__ A, const float* __restrict__ B,
    const float* __restrict__ bias, const float* __restrict__ res,
    float* __restrict__ C, int M, int N, int K) {
  __shared__ float As[16][65];
  __shared__ float Bs[16][65];
  int tid = threadIdx.x;
  int tx = tid & 15, ty = tid >> 4;
  int bm = blockIdx.x * 64, bn = blockIdx.y * 64;
  float acc[4][4] = {};
  for (int k0 = 0; k0 < K; k0 += 16) {
    if (ATRANS) {
      #pragma unroll
      for (int i = 0; i < 4; i++) {
        int e = tid + i*256;
        int m = e & 63, kk = e >> 6;
        int gm = bm + m;
        As[kk][m] = (gm < M) ? A[(size_t)(k0+kk)*M + gm] : 0.f;
      }
    } else {
      #pragma unroll
      for (int i = 0; i < 4; i++) {
        int e = tid + i*256;
        int kk = e & 15, m = e >> 4;
        int gm = bm + m;
        As[kk][m] = (gm < M) ? A[(size_t)gm*K + (k0+kk)] : 0.f;
      }
    }
    #pragma unroll
    for (int i = 0; i < 4; i++) {
      int e = tid + i*256;
      int n = e & 63, kk = e >> 6;
      int gnn = bn + n;
      Bs[kk][n] = (gnn < N) ? B[(size_t)(k0+kk)*N + gnn] : 0.f;
    }
    __syncthreads();
    #pragma unroll
    for (int kk = 0; kk < 16; kk++) {
      float a0[4], b0[4];
      #pragma unroll
      for (int i = 0; i < 4; i++) a0[i] = As[kk][ty*4+i];
      #pragma unroll
      for (int j = 0; j < 4; j++) b0[j] = Bs[kk][tx*4+j];
      #pragma unroll
      for (int i = 0; i < 4; i++)
        #pragma unroll
        for (int j = 0; j < 4; j++) acc[i][j] = fmaf(a0[i], b0[j], acc[i][j]);
    }
    __syncthreads();
  }
  #pragma unroll
  for (int i = 0; i < 4; i++) {
    int m = bm + ty*4 + i;
    if (m >= M) continue;
    #pragma unroll
    for (int j = 0; j < 4; j++) {
      int n = bn + tx*4 + j;
      if (n >= N) continue;
      float vv = acc[i][j];
      if (bias) vv += bias[n];
      if (res)  vv += res[(size_t)m*N + n];
      C[(size_t)m*N + n] = vv;
    }
  }
}

// ---------------- GEGLU GEMM ----------------
__global__ __launch_bounds__(256) void geglu_kernel(
    const float* __restrict__ A, const float* __restrict__ B,
    const float* __restrict__ bias, float* __restrict__ C, int K) {
  __shared__ float As[16][65];
  __shared__ float Ba[16][65];
  __shared__ float Bg[16][65];
  int tid = threadIdx.x;
  int tx = tid & 15, ty = tid >> 4;
  int bm = blockIdx.x * 64, bn = blockIdx.y * 64;
  float acca[4][4] = {}, accg[4][4] = {};
  for (int k0 = 0; k0 < K; k0 += 16) {
    #pragma unroll
    for (int i = 0; i < 4; i++) {
      int e = tid + i*256;
      int kk = e & 15, m = e >> 4;
      As[kk][m] = A[(size_t)(bm+m)*K + (k0+kk)];
    }
    #pragma unroll
    for (int i = 0; i < 4; i++) {
      int e = tid + i*256;
      int n = e & 63, kk = e >> 6;
      Ba[kk][n] = B[(size_t)(k0+kk)*2560 + bn + n];
      Bg[kk][n] = B[(size_t)(k0+kk)*2560 + 1280 + bn + n];
    }
    __syncthreads();
    #pragma unroll
    for (int kk = 0; kk < 16; kk++) {
      float a0[4], ba[4], bg[4];
      #pragma unroll
      for (int i = 0; i < 4; i++) a0[i] = As[kk][ty*4+i];
      #pragma unroll
      for (int j = 0; j < 4; j++) { ba[j] = Ba[kk][tx*4+j]; bg[j] = Bg[kk][tx*4+j]; }
      #pragma unroll
      for (int i = 0; i < 4; i++)
        #pragma unroll
        for (int j = 0; j < 4; j++) {
          acca[i][j] = fmaf(a0[i], ba[j], acca[i][j]);
          accg[i][j] = fmaf(a0[i], bg[j], accg[i][j]);
        }
    }
    __syncthreads();
  }
  #pragma unroll
  for (int i = 0; i < 4; i++) {
    int m = bm + ty*4 + i;
    #pragma unroll
    for (int j = 0; j < 4; j++) {
      int n = bn + tx*4 + j;
      float a = acca[i][j] + bias[n];
      float g = accg[i][j] + bias[1280 + n];
      float gl = 0.5f * g * (1.f + erff(g * 0.70710678118654752f));
      C[(size_t)m*1280 + n] = a * gl;
    }
  }
}

// ---------------- proj_out GEMM ----------------
__global__ __launch_bounds__(256) void projout_kernel(
    const float* __restrict__ A, const float* __restrict__ B,
    const float* __restrict__ bias, const float* __restrict__ xin,
    float* __restrict__ out) {
  __shared__ float As[16][65];
  __shared__ float Bs[16][65];
  int tid = threadIdx.x;
  int tx = tid & 15, ty = tid >> 4;
  int bm = blockIdx.x * 64, bn = blockIdx.y * 64;
  float acc[4][4] = {};
  for (int k0 = 0; k0 < 320; k0 += 16) {
    #pragma unroll
    for (int i = 0; i < 4; i++) {
      int e = tid + i*256;
      int kk = e & 15, m = e >> 4;
      As[kk][m] = A[(size_t)(bm+m)*320 + (k0+kk)];
    }
    #pragma unroll
    for (int i = 0; i < 4; i++) {
      int e = tid + i*256;
      int n = e & 63, kk = e >> 6;
      Bs[kk][n] = B[(size_t)(k0+kk)*320 + bn + n];
    }
    __syncthreads();
    #pragma unroll
    for (int kk = 0; kk < 16; kk++) {
      float a0[4], b0[4];
      #pragma unroll
      for (int i = 0; i < 4; i++) a0[i] = As[kk][ty*4+i];
      #pragma unroll
      for (int j = 0; j < 4; j++) b0[j] = Bs[kk][tx*4+j];
      #pragma unroll
      for (int i = 0; i < 4; i++)
        #pragma unroll
        for (int j = 0; j < 4; j++) acc[i][j] = fmaf(a0[i], b0[j], acc[i][j]);
    }
    __syncthreads();
  }
  #pragma unroll
  for (int i = 0; i < 4; i++) {
    int m = bm + ty*4 + i;
    #pragma unroll
    for (int j = 0; j < 4; j++) {
      int n = bn + tx*4 + j;
      out[(size_t)n*4096 + m] = acc[i][j] + bias[n] + xin[(size_t)n*4096 + m];
    }
  }
}

// ---------------- Self-attention: flash MFMA, S^T=K·Q^T / O^T=V^T·P^T ----------------
// Block: 256 thr (4 waves), each wave owns 16 queries; TQ=64/block, TK=64.
// Grid: (4096/64, 8 heads) = 512 blocks -> 8 waves/CU.
__global__ __launch_bounds__(256) void self_attn_mfma(
    const float* __restrict__ Q, const float* __restrict__ K,
    const float* __restrict__ V, float* __restrict__ O) {
  const int h = blockIdx.y;
  const int q0 = blockIdx.x * 64;
  const int tid = threadIdx.x;
  const int w = tid >> 6, lane = tid & 63;
  const int l16 = lane & 15, g = lane >> 4;

  // stride 72 halfwords = 144 B: 16B-aligned rows, 36-word stride (2-way banks)
  __shared__ __align__(16) unsigned short Kls[64][72];   // [key][d 0..63, d>=40 zero]
  __shared__ __align__(16) unsigned short Vt[48][72];    // [d 0..47 (40..47 zero)][key]
  __shared__ __align__(16) unsigned short PsT[4][16][72];// per wave: [q][key]

  // zero the never-restaged pad regions once
  for (int e = tid; e < 64*12; e += 256) {              // Kls cols 40..63
    int r = e / 12, c = e % 12;
    *(unsigned*)&Kls[r][40 + 2*c] = 0u;
  }
  for (int e = tid; e < 8*32; e += 256) {               // Vt rows 40..47, keys 0..63
    int r = 40 + (e >> 5), c = e & 31;
    *(unsigned*)&Vt[r][2*c] = 0u;
  }

  // Q B-frags (register-resident): B[k=d][n=q], lane holds d = ks*32+g*8+j
  short8v Qb[2];
  {
    const float* qrow = Q + (size_t)(q0 + w*16 + l16)*320 + h*40;
    #pragma unroll
    for (int ks = 0; ks < 2; ks++) {
      union { short8v v; unsigned short u[8]; } t;
      #pragma unroll
      for (int j = 0; j < 8; j++) {
        int d = ks*32 + g*8 + j;
        t.u[j] = (d < 40) ? f2bf(qrow[d] * SCALE_ATTN) : (unsigned short)0;
      }
      Qb[ks] = t.v;
    }
  }

  float m_i = -1e30f, l_i = 0.f;
  float4v Of[3] = {};   // O^T frags: rows d = mt*16+4g+reg, col q = l16

  for (int kt = 0; kt < 4096; kt += 64) {
    __syncthreads();  // prior iter's LDS reads done
    // stage K tile: Kls[key][d] bf16, packed pair writes
    for (int e = tid; e < 1280; e += 256) {
      int key = e / 20, dp = e % 20;
      float2 kv = *(const float2*)&K[(size_t)(kt+key)*320 + h*40 + dp*2];
      *(unsigned*)&Kls[key][dp*2] = pack2(kv.x, kv.y);
    }
    // stage V transposed: Vt[d][key]
    for (int e = tid; e < 1280; e += 256) {
      int kp = e / 40, d = e % 40;
      float v0 = V[(size_t)(kt + kp*2    )*320 + h*40 + d];
      float v1 = V[(size_t)(kt + kp*2 + 1)*320 + h*40 + d];
      *(unsigned*)&Vt[d][kp*2] = pack2(v0, v1);
    }
    __syncthreads();  // staged tiles visible

    // S^T = K·Q^T: A=K[m=key][k=d] from LDS, B=Q^T regs
    float4v Sf[4];
    #pragma unroll
    for (int mt = 0; mt < 4; mt++) {
      short8v ka0 = *(const short8v*)&Kls[mt*16 + l16][g*8];
      short8v ka1 = *(const short8v*)&Kls[mt*16 + l16][32 + g*8];
      float4v s = {};
      s = __builtin_amdgcn_mfma_f32_16x16x32_bf16(ka0, Qb[0], s, 0, 0, 0);
      s = __builtin_amdgcn_mfma_f32_16x16x32_bf16(ka1, Qb[1], s, 0, 0, 0);
      Sf[mt] = s;
    }

    // online softmax: all 16 regs of this lane belong to query q=l16
    float mx = -1e30f;
    #pragma unroll
    for (int mt = 0; mt < 4; mt++)
      #pragma unroll
      for (int r = 0; r < 4; r++) mx = fmaxf(mx, Sf[mt][r]);
    mx = fmaxf(mx, __shfl_xor(mx, 16));
    mx = fmaxf(mx, __shfl_xor(mx, 32));
    float mnew = fmaxf(m_i, mx);
    float alpha = __expf(m_i - mnew);
    float rsum = 0.f;
    #pragma unroll
    for (int mt = 0; mt < 4; mt++)
      #pragma unroll
      for (int r = 0; r < 4; r++) {
        float p = __expf(Sf[mt][r] - mnew);
        Sf[mt][r] = p; rsum += p;
      }
    rsum += __shfl_xor(rsum, 16);
    rsum += __shfl_xor(rsum, 32);
    l_i = l_i * alpha + rsum;
    m_i = mnew;
    #pragma unroll
    for (int mt = 0; mt < 3; mt++)
      #pragma unroll
      for (int r = 0; r < 4; r++) Of[mt][r] *= alpha;

    // write P^T (bf16) to LDS: keys mt*16+4g+reg are consecutive -> b64
    #pragma unroll
    for (int mt = 0; mt < 4; mt++) {
      uint2 pk;
      pk.x = pack2(Sf[mt][0], Sf[mt][1]);
      pk.y = pack2(Sf[mt][2], Sf[mt][3]);
      *(uint2*)&PsT[w][l16][mt*16 + 4*g] = pk;
    }
    __syncthreads();  // P^T visible (cross-lane within wave)

    // O^T += V^T · P^T : A=V^T[m=d][k=key] from Vt, B=P^T[k=key][n=q] from PsT
    #pragma unroll
    for (int ks = 0; ks < 2; ks++) {
      short8v pb = *(const short8v*)&PsT[w][l16][ks*32 + g*8];
      #pragma unroll
      for (int mt = 0; mt < 3; mt++) {
        short8v va = *(const short8v*)&Vt[mt*16 + l16][ks*32 + g*8];
        Of[mt] = __builtin_amdgcn_mfma_f32_16x16x32_bf16(va, pb, Of[mt], 0, 0, 0);
      }
    }
  }

  // epilogue: O[q][h*40+d] = O^T[d][q] / l
  float inv = 1.f / l_i;
  float* orow = O + (size_t)(q0 + w*16 + l16)*320 + h*40;
  #pragma unroll
  for (int mt = 0; mt < 3; mt++) {
    #pragma unroll
    for (int rp = 0; rp < 2; rp++) {
      int d = mt*16 + 4*g + rp*2;
      if (d < 40) {
        float2 val = { Of[mt][rp*2] * inv, Of[mt][rp*2+1] * inv };
        *(float2*)&orow[d] = val;
      }
    }
  }
}

// ---------------- Cross-attention: one thread per (s, head), 77 keys ----------------
__global__ __launch_bounds__(256) void cross_attn_kernel(
    const float* __restrict__ Q, const float* __restrict__ Kc,
    const float* __restrict__ Vc, float* __restrict__ O) {
  int gid = blockIdx.x * 256 + threadIdx.x;
  int h = gid & 7;
  int s = gid >> 3;
  const float* qp = Q + (size_t)s*320 + h*40;
  float qr[40];
  #pragma unroll
  for (int d = 0; d < 40; d++) qr[d] = qp[d] * SCALE_ATTN;
  float m = -3.0e38f, l = 0.f, acc[40];
  #pragma unroll
  for (int d = 0; d < 40; d++) acc[d] = 0.f;
  for (int t = 0; t < 77; t++) {
    const float* kp = Kc + (size_t)t*320 + h*40;
    float x = 0.f;
    #pragma unroll
    for (int d = 0; d < 40; d++) x = fmaf(qr[d], kp[d], x);
    float mn = fmaxf(m, x);
    float al = __expf(m - mn);
    float p = __expf(x - mn);
    m = mn;
    l = l*al + p;
    const float* vp = Vc + (size_t)t*320 + h*40;
    #pragma unroll
    for (int d = 0; d < 40; d++) acc[d] = acc[d]*al + p*vp[d];
  }
  float inv = 1.f/l;
  float* op = O + (size_t)s*320 + h*40;
  #pragma unroll
  for (int d = 0; d < 40; d++) op[d] = acc[d]*inv;
}

extern "C" void kernel_launch(void* const* d_in, const int* in_sizes, int n_in,
                              void* d_out, int out_size, void* d_ws, size_t ws_size,
                              hipStream_t stream) {
  const float* x        = (const float*)d_in[0];
  const float* ctx      = (const float*)d_in[1];
  const float* gn_s     = (const float*)d_in[2];
  const float* gn_b     = (const float*)d_in[3];
  const float* w_pin    = (const float*)d_in[4];
  const float* b_pin    = (const float*)d_in[5];
  const float* ln1_s    = (const float*)d_in[6];
  const float* ln1_b    = (const float*)d_in[7];
  const float* wq1      = (const float*)d_in[8];
  const float* wk1      = (const float*)d_in[9];
  const float* wv1      = (const float*)d_in[10];
  const float* wo1      = (const float*)d_in[11];
  const float* bo1      = (const float*)d_in[12];
  const float* ln2_s    = (const float*)d_in[13];
  const float* ln2_b    = (const float*)d_in[14];
  const float* wq2      = (const float*)d_in[15];
  const float* wk2      = (const float*)d_in[16];
  const float* wv2      = (const float*)d_in[17];
  const float* wo2      = (const float*)d_in[18];
  const float* bo2      = (const float*)d_in[19];
  const float* ln3_s    = (const float*)d_in[20];
  const float* ln3_b    = (const float*)d_in[21];
  const float* w_ff1    = (const float*)d_in[22];
  const float* b_ff1    = (const float*)d_in[23];
  const float* w_ff2    = (const float*)d_in[24];
  const float* b_ff2    = (const float*)d_in[25];
  const float* w_pout   = (const float*)d_in[26];
  const float* b_pout   = (const float*)d_in[27];
  float* out = (float*)d_out;

  // Aliased workspace: 6 x HB floats = 31.5 MB total.
  float* ws = (float*)d_ws;
  const size_t HB = 4096u*320u;
  float* h    = ws + 0*HB;
  float* hn   = ws + 1*HB;
  float* q    = ws + 2*HB;
  float* k    = ws + 3*HB;
  float* v    = ws + 4*HB;
  float* ao   = ws + 5*HB;
  float* gn   = k;
  float* gg   = q;
  float* kc   = k;
  float* vc   = k + 77*320;

  dim3 g64x5(64, 5), blk(256);

  hipLaunchKernelGGL(groupnorm_kernel, dim3(32), blk, 0, stream, x, gn_s, gn_b, gn);
  hipLaunchKernelGGL((gemm_kernel<true>), g64x5, blk, 0, stream, gn, w_pin, b_pin, (const float*)nullptr, h, 4096, 320, 320);
  hipLaunchKernelGGL(layernorm_kernel, dim3(4096), dim3(64), 0, stream, h, ln1_s, ln1_b, hn);
  hipLaunchKernelGGL((gemm_kernel<false>), g64x5, blk, 0, stream, hn, wq1, (const float*)nullptr, (const float*)nullptr, q, 4096, 320, 320);
  hipLaunchKernelGGL((gemm_kernel<false>), g64x5, blk, 0, stream, hn, wk1, (const float*)nullptr, (const float*)nullptr, k, 4096, 320, 320);
  hipLaunchKernelGGL((gemm_kernel<false>), g64x5, blk, 0, stream, hn, wv1, (const float*)nullptr, (const float*)nullptr, v, 4096, 320, 320);
  hipLaunchKernelGGL(self_attn_mfma, dim3(64, 8), blk, 0, stream, q, k, v, ao);
  hipLaunchKernelGGL((gemm_kernel<false>), g64x5, blk, 0, stream, ao, wo1, bo1, h, h, 4096, 320, 320);
  hipLaunchKernelGGL(layernorm_kernel, dim3(4096), dim3(64), 0, stream, h, ln2_s, ln2_b, hn);
  hipLaunchKernelGGL((gemm_kernel<false>), g64x5, blk, 0, stream, hn, wq2, (const float*)nullptr, (const float*)nullptr, q, 4096, 320, 320);
  hipLaunchKernelGGL((gemm_kernel<false>), dim3(2, 5), blk, 0, stream, ctx, wk2, (const float*)nullptr, (const float*)nullptr, kc, 77, 320, 768);
  hipLaunchKernelGGL((gemm_kernel<false>), dim3(2, 5), blk, 0, stream, ctx, wv2, (const float*)nullptr, (const float*)nullptr, vc, 77, 320, 768);
  hipLaunchKernelGGL(cross_attn_kernel, dim3(128), blk, 0, stream, q, kc, vc, ao);
  hipLaunchKernelGGL((gemm_kernel<false>), g64x5, blk, 0, stream, ao, wo2, bo2, h, h, 4096, 320, 320);
  hipLaunchKernelGGL(layernorm_kernel, dim3(4096), dim3(64), 0, stream, h, ln3_s, ln3_b, hn);
  hipLaunchKernelGGL(geglu_kernel, dim3(64, 20), blk, 0, stream, hn, w_ff1, b_ff1, gg, 320);
  hipLaunchKernelGGL((gemm_kernel<false>), g64x5, blk, 0, stream, gg, w_ff2, b_ff2, h, h, 4096, 320, 1280);
  hipLaunchKernelGGL(projout_kernel, g64x5, blk, 0, stream, h, w_pout, b_pout, x, out);
}

// Round 4
// 624.049 us; speedup vs baseline: 4.1760x; 2.2347x over previous
//
#include <hip/hip_runtime.h>
#include <math.h>

#define SCALE_ATTN 0.15811388300841897f

typedef __attribute__((ext_vector_type(8))) short short8v;
typedef __attribute__((ext_vector_type(4))) float float4v;
typedef unsigned short u16;

__device__ __forceinline__ u16 f2bf(float x) {
  unsigned u = __float_as_uint(x);
  unsigned r = (u + 0x7FFFu + ((u >> 16) & 1u)) >> 16;
  return (u16)r;
}
__device__ __forceinline__ unsigned pack2(float a, float b) {
  return (unsigned)f2bf(a) | ((unsigned)f2bf(b) << 16);
}
__device__ __forceinline__ float bfu2f(u16 u) {
  return __uint_as_float(((unsigned)u) << 16);
}

// ---------------- weight transpose+convert: W[K,N] fp32 -> WT[N,K] bf16 ----------------
struct TDesc { const float* src; u16* dst; int K, N, off, tx; };
struct TPack { TDesc d[12]; };

__global__ __launch_bounds__(256) void tcvt_kernel(TPack p) {
  __shared__ float ls[32][33];
  int bt = blockIdx.x, t = threadIdx.x;
  int ti = 0;
  #pragma unroll
  for (int i = 1; i < 12; i++) if (bt >= p.d[i].off) ti = i;
  TDesc dd = p.d[ti];
  int local = bt - dd.off;
  int n0 = (local % dd.tx) * 32, k0 = (local / dd.tx) * 32;
  #pragma unroll
  for (int i = 0; i < 4; i++) {
    int idx = t + i*256, r = idx >> 5, c = idx & 31;
    ls[r][c] = dd.src[(size_t)(k0 + r)*dd.N + n0 + c];
  }
  __syncthreads();
  #pragma unroll
  for (int i = 0; i < 2; i++) {
    int p2 = t + i*256, n = p2 >> 4, kp = (p2 & 15)*2;
    *(unsigned*)&dd.dst[(size_t)(n0 + n)*dd.K + k0 + kp] = pack2(ls[kp][n], ls[kp+1][n]);
  }
}

// ---------------- ctx fp32 -> bf16 (77*768 = 59136) ----------------
__global__ __launch_bounds__(256) void ctx_cvt_kernel(const float* __restrict__ src, u16* __restrict__ dst) {
  int idx = (blockIdx.x*256 + threadIdx.x)*4;
  if (idx < 59136) {
    float4 v = *(const float4*)&src[idx];
    uint2 o; o.x = pack2(v.x, v.y); o.y = pack2(v.z, v.w);
    *(uint2*)&dst[idx] = o;
  }
}

// ---------------- GroupNorm stats -> per-channel scale/shift ----------------
__global__ __launch_bounds__(256) void gn_stats_kernel(
    const float* __restrict__ x, const float* __restrict__ gs,
    const float* __restrict__ gb, float* __restrict__ chscale, float* __restrict__ chshift) {
  int g = blockIdx.x, tid = threadIdx.x;
  size_t base = (size_t)g * 40960;
  float sum = 0.f, sq = 0.f;
  for (int e = tid; e < 40960; e += 256) {
    float v = x[base + e];
    sum += v; sq += v * v;
  }
  __shared__ float s1[256], s2[256];
  s1[tid] = sum; s2[tid] = sq; __syncthreads();
  for (int st = 128; st > 0; st >>= 1) {
    if (tid < st) { s1[tid] += s1[tid+st]; s2[tid] += s2[tid+st]; }
    __syncthreads();
  }
  float mu = s1[0] * (1.f/40960.f);
  float var = s2[0] * (1.f/40960.f) - mu*mu;
  float rs = rsqrtf(var + 1e-6f);
  if (tid < 10) {
    int c = g*10 + tid;
    float sc = rs * gs[c];
    chscale[c] = sc;
    chshift[c] = gb[c] - mu * sc;
  }
}

// ---------------- GN apply + transpose: x[c][s] fp32 -> gnT[s][c] bf16 ----------------
__global__ __launch_bounds__(256) void gn_apply_t_kernel(
    const float* __restrict__ x, const float* __restrict__ chscale,
    const float* __restrict__ chshift, u16* __restrict__ gnT) {
  __shared__ float ts[64][65];
  __shared__ float scl[64], sft[64];
  int s0 = blockIdx.x * 64, c0 = blockIdx.y * 64;
  int t = threadIdx.x;
  if (t < 64) { scl[t] = chscale[c0 + t]; sft[t] = chshift[c0 + t]; }
  int crow = t >> 2, sch = (t & 3) * 16;
  #pragma unroll
  for (int j = 0; j < 4; j++) {
    float4 v = *(const float4*)&x[(size_t)(c0 + crow)*4096 + s0 + sch + 4*j];
    ts[crow][sch + 4*j + 0] = v.x; ts[crow][sch + 4*j + 1] = v.y;
    ts[crow][sch + 4*j + 2] = v.z; ts[crow][sch + 4*j + 3] = v.w;
  }
  __syncthreads();
  int srow = t >> 2, cch = (t & 3) * 16;
  #pragma unroll
  for (int p = 0; p < 8; p++) {
    int cl = cch + 2*p;
    float f0 = ts[cl][srow] * scl[cl] + sft[cl];
    float f1 = ts[cl+1][srow] * scl[cl+1] + sft[cl+1];
    *(unsigned*)&gnT[(size_t)(s0 + srow)*320 + c0 + cl] = pack2(f0, f1);
  }
}

// ---------------- LayerNorm bf16->bf16: one wave per row of 320 ----------------
__global__ __launch_bounds__(64) void layernorm_kernel(
    const u16* __restrict__ X, const float* __restrict__ s,
    const float* __restrict__ b, u16* __restrict__ Y) {
  int row = blockIdx.x, t = threadIdx.x;
  const u16* xr = X + (size_t)row*320;
  float v[5], sum = 0.f, sq = 0.f;
  #pragma unroll
  for (int i = 0; i < 5; i++) { v[i] = bfu2f(xr[t + 64*i]); sum += v[i]; sq += v[i]*v[i]; }
  #pragma unroll
  for (int o = 32; o > 0; o >>= 1) { sum += __shfl_down(sum, o); sq += __shfl_down(sq, o); }
  sum = __shfl(sum, 0); sq = __shfl(sq, 0);
  float mu = sum * (1.f/320.f);
  float var = sq * (1.f/320.f) - mu*mu;
  float rs = rsqrtf(var + 1e-5f);
  u16* yr = Y + (size_t)row*320;
  #pragma unroll
  for (int i = 0; i < 5; i++) {
    int c = t + 64*i;
    yr[c] = f2bf((v[i]-mu)*rs*s[c] + b[c]);
  }
}

// ---------------- MFMA GEMM: C[M,N] = A[M,K](bf16) * BT[N,K](bf16)^T ----------------
// MODE 0: bf16 out, optional fp32 bias[n], optional bf16 res[m*N+n]
// MODE 2: proj_out: fp32 out[n*4096+m] = acc + bias[n] + xres[n*4096+m]
template<int MODE>
__global__ __launch_bounds__(256) void mgemm(
    const u16* __restrict__ A, const u16* __restrict__ BT,
    const float* __restrict__ bias, const u16* __restrict__ res,
    const float* __restrict__ xres, void* __restrict__ Cout,
    int M, int N, int K) {
  __shared__ __align__(16) u16 smem[2*64*72];
  u16* As = smem;
  u16* Bs = smem + 64*72;
  const int t = threadIdx.x;
  const int lane = t & 63, w = t >> 6, l16 = lane & 15, g = lane >> 4;
  const int bm = blockIdx.x * 64, bn = blockIdx.y * 64;
  const int m0 = (w & 1) * 32, n0 = (w >> 1) * 32;
  float4v acc[2][2] = {};
  const int ar = t >> 2, ac = (t & 3) * 16;
  const bool aok = (bm + ar) < M;

  for (int k0 = 0; k0 < K; k0 += 64) {
    __syncthreads();
    short8v a0 = {}, a1 = {};
    if (aok) {
      const u16* ga = &A[(size_t)(bm + ar)*K + k0 + ac];
      a0 = *(const short8v*)ga; a1 = *(const short8v*)(ga + 8);
    }
    *(short8v*)&As[ar*72 + ac] = a0;
    *(short8v*)&As[ar*72 + ac + 8] = a1;
    const u16* gbp = &BT[(size_t)(bn + ar)*K + k0 + ac];
    *(short8v*)&Bs[ar*72 + ac] = *(const short8v*)gbp;
    *(short8v*)&Bs[ar*72 + ac + 8] = *(const short8v*)(gbp + 8);
    __syncthreads();
    #pragma unroll
    for (int ks = 0; ks < 2; ks++) {
      short8v af[2], bfv[2];
      #pragma unroll
      for (int mt = 0; mt < 2; mt++)
        af[mt] = *(const short8v*)&As[(m0 + 16*mt + l16)*72 + ks*32 + g*8];
      #pragma unroll
      for (int nt = 0; nt < 2; nt++)
        bfv[nt] = *(const short8v*)&Bs[(n0 + 16*nt + l16)*72 + ks*32 + g*8];
      #pragma unroll
      for (int mt = 0; mt < 2; mt++)
        #pragma unroll
        for (int nt = 0; nt < 2; nt++)
          acc[mt][nt] = __builtin_amdgcn_mfma_f32_16x16x32_bf16(af[mt], bfv[nt], acc[mt][nt], 0, 0, 0);
    }
  }
  __syncthreads();
  float* Cs = (float*)smem;  // [64][68], 17408 B
  #pragma unroll
  for (int mt = 0; mt < 2; mt++)
    #pragma unroll
    for (int nt = 0; nt < 2; nt++)
      #pragma unroll
      for (int r = 0; r < 4; r++)
        Cs[(m0 + 16*mt + 4*g + r)*68 + n0 + 16*nt + l16] = acc[mt][nt][r];
  __syncthreads();

  if (MODE == 0) {
    u16* C = (u16*)Cout;
    #pragma unroll
    for (int i = 0; i < 8; i++) {
      int p = t + i*256;
      int mm = p >> 5, nn = (p & 31)*2;
      int gm = bm + mm;
      if (gm >= M) continue;
      float f0 = Cs[mm*68 + nn], f1 = Cs[mm*68 + nn + 1];
      if (bias) { f0 += bias[bn + nn]; f1 += bias[bn + nn + 1]; }
      if (res) {
        unsigned u = *(const unsigned*)&res[(size_t)gm*N + bn + nn];
        f0 += bfu2f((u16)(u & 0xffffu));
        f1 += bfu2f((u16)(u >> 16));
      }
      *(unsigned*)&C[(size_t)gm*N + bn + nn] = pack2(f0, f1);
    }
  } else {
    float* C = (float*)Cout;
    int nloc = t >> 2, mch = (t & 3) * 16;
    float bb = bias[bn + nloc];
    #pragma unroll
    for (int j = 0; j < 4; j++) {
      int m4 = mch + j*4;
      float4 xv = *(const float4*)&xres[(size_t)(bn + nloc)*4096 + bm + m4];
      float4 ov;
      ov.x = Cs[(m4+0)*68 + nloc] + bb + xv.x;
      ov.y = Cs[(m4+1)*68 + nloc] + bb + xv.y;
      ov.z = Cs[(m4+2)*68 + nloc] + bb + xv.z;
      ov.w = Cs[(m4+3)*68 + nloc] + bb + xv.w;
      *(float4*)&C[(size_t)(bn + nloc)*4096 + bm + m4] = ov;
    }
  }
}

// ---------------- GEGLU MFMA: gg[s][j] = (A·W[:,j]+b[j]) * gelu(A·W[:,1280+j]+b[1280+j]) ----------------
__global__ __launch_bounds__(256) void geglu_mfma(
    const u16* __restrict__ A, const u16* __restrict__ BT,
    const float* __restrict__ bias, u16* __restrict__ C) {
  __shared__ __align__(16) u16 smem[3*64*72];
  u16* As = smem;
  u16* Ba = smem + 64*72;
  u16* Bg = smem + 2*64*72;
  const int t = threadIdx.x;
  const int lane = t & 63, w = t >> 6, l16 = lane & 15, g = lane >> 4;
  const int bm = blockIdx.x * 64, bn = blockIdx.y * 64;
  const int m0 = (w & 1) * 32, n0 = (w >> 1) * 32;
  float4v aacc[2][2] = {}, gacc[2][2] = {};
  const int ar = t >> 2, ac = (t & 3) * 16;

  for (int k0 = 0; k0 < 320; k0 += 64) {
    __syncthreads();
    {
      const u16* ga = &A[(size_t)(bm + ar)*320 + k0 + ac];
      *(short8v*)&As[ar*72 + ac] = *(const short8v*)ga;
      *(short8v*)&As[ar*72 + ac + 8] = *(const short8v*)(ga + 8);
      const u16* gba = &BT[(size_t)(bn + ar)*320 + k0 + ac];
      *(short8v*)&Ba[ar*72 + ac] = *(const short8v*)gba;
      *(short8v*)&Ba[ar*72 + ac + 8] = *(const short8v*)(gba + 8);
      const u16* gbg = &BT[(size_t)(1280 + bn + ar)*320 + k0 + ac];
      *(short8v*)&Bg[ar*72 + ac] = *(const short8v*)gbg;
      *(short8v*)&Bg[ar*72 + ac + 8] = *(const short8v*)(gbg + 8);
    }
    __syncthreads();
    #pragma unroll
    for (int ks = 0; ks < 2; ks++) {
      short8v af[2], bav[2], bgv[2];
      #pragma unroll
      for (int mt = 0; mt < 2; mt++)
        af[mt] = *(const short8v*)&As[(m0 + 16*mt + l16)*72 + ks*32 + g*8];
      #pragma unroll
      for (int nt = 0; nt < 2; nt++) {
        bav[nt] = *(const short8v*)&Ba[(n0 + 16*nt + l16)*72 + ks*32 + g*8];
        bgv[nt] = *(const short8v*)&Bg[(n0 + 16*nt + l16)*72 + ks*32 + g*8];
      }
      #pragma unroll
      for (int mt = 0; mt < 2; mt++)
        #pragma unroll
        for (int nt = 0; nt < 2; nt++) {
          aacc[mt][nt] = __builtin_amdgcn_mfma_f32_16x16x32_bf16(af[mt], bav[nt], aacc[mt][nt], 0, 0, 0);
          gacc[mt][nt] = __builtin_amdgcn_mfma_f32_16x16x32_bf16(af[mt], bgv[nt], gacc[mt][nt], 0, 0, 0);
        }
    }
  }
  __syncthreads();
  float* Cs = (float*)smem;  // [64][68] fits in As+Ba
  #pragma unroll
  for (int nt = 0; nt < 2; nt++) {
    int col = n0 + 16*nt + l16;
    float ba = bias[bn + col];
    float bg2 = bias[1280 + bn + col];
    #pragma unroll
    for (int mt = 0; mt < 2; mt++)
      #pragma unroll
      for (int r = 0; r < 4; r++) {
        float a = aacc[mt][nt][r] + ba;
        float gv = gacc[mt][nt][r] + bg2;
        float gl = 0.5f * gv * (1.f + erff(gv * 0.70710678118654752f));
        Cs[(m0 + 16*mt + 4*g + r)*68 + col] = a * gl;
      }
  }
  __syncthreads();
  #pragma unroll
  for (int i = 0; i < 8; i++) {
    int p = t + i*256;
    int mm = p >> 5, nn = (p & 31)*2;
    *(unsigned*)&C[(size_t)(bm + mm)*1280 + bn + nn] = pack2(Cs[mm*68 + nn], Cs[mm*68 + nn + 1]);
  }
}

// ---------------- Self-attention: flash MFMA, bf16 I/O ----------------
__global__ __launch_bounds__(256) void self_attn_mfma(
    const u16* __restrict__ Q, const u16* __restrict__ K,
    const u16* __restrict__ V, u16* __restrict__ O) {
  const int h = blockIdx.y;
  const int q0 = blockIdx.x * 64;
  const int tid = threadIdx.x;
  const int w = tid >> 6, lane = tid & 63;
  const int l16 = lane & 15, g = lane >> 4;

  __shared__ __align__(16) u16 Kls[64][72];
  __shared__ __align__(16) u16 Vt[48][72];
  __shared__ __align__(16) u16 PsT[4][16][72];

  for (int e = tid; e < 64*12; e += 256) {
    int r = e / 12, c = e % 12;
    *(unsigned*)&Kls[r][40 + 2*c] = 0u;
  }
  for (int e = tid; e < 8*32; e += 256) {
    int r = 40 + (e >> 5), c = e & 31;
    *(unsigned*)&Vt[r][2*c] = 0u;
  }

  // Q B-frags: lane holds d = ks*32+g*8+j for its query q0+w*16+l16
  short8v Qb[2];
  {
    const u16* qrow = Q + (size_t)(q0 + w*16 + l16)*320 + h*40;
    Qb[0] = *(const short8v*)(qrow + g*8);
    short8v z = {};
    Qb[1] = (g == 0) ? *(const short8v*)(qrow + 32) : z;
  }

  float m_i = -1e30f, l_i = 0.f;
  float4v Of[3] = {};

  for (int kt = 0; kt < 4096; kt += 64) {
    __syncthreads();
    for (int e = tid; e < 1280; e += 256) {
      int key = e / 20, dp = e % 20;
      *(unsigned*)&Kls[key][dp*2] =
        *(const unsigned*)&K[(size_t)(kt + key)*320 + h*40 + dp*2];
    }
    for (int e = tid; e < 1280; e += 256) {
      int kp = e / 40, d = e % 40;
      unsigned u0 = V[(size_t)(kt + kp*2    )*320 + h*40 + d];
      unsigned u1 = V[(size_t)(kt + kp*2 + 1)*320 + h*40 + d];
      *(unsigned*)&Vt[d][kp*2] = u0 | (u1 << 16);
    }
    __syncthreads();

    float4v Sf[4];
    #pragma unroll
    for (int mt = 0; mt < 4; mt++) {
      short8v ka0 = *(const short8v*)&Kls[mt*16 + l16][g*8];
      short8v ka1 = *(const short8v*)&Kls[mt*16 + l16][32 + g*8];
      float4v s = {};
      s = __builtin_amdgcn_mfma_f32_16x16x32_bf16(ka0, Qb[0], s, 0, 0, 0);
      s = __builtin_amdgcn_mfma_f32_16x16x32_bf16(ka1, Qb[1], s, 0, 0, 0);
      Sf[mt] = s;
    }

    float mx = -1e30f;
    #pragma unroll
    for (int mt = 0; mt < 4; mt++)
      #pragma unroll
      for (int r = 0; r < 4; r++) mx = fmaxf(mx, Sf[mt][r]);
    mx = fmaxf(mx, __shfl_xor(mx, 16));
    mx = fmaxf(mx, __shfl_xor(mx, 32));
    float mnew = fmaxf(m_i, mx);
    float alpha = __expf((m_i - mnew) * SCALE_ATTN);
    float rsum = 0.f;
    #pragma unroll
    for (int mt = 0; mt < 4; mt++)
      #pragma unroll
      for (int r = 0; r < 4; r++) {
        float p = __expf((Sf[mt][r] - mnew) * SCALE_ATTN);
        Sf[mt][r] = p; rsum += p;
      }
    rsum += __shfl_xor(rsum, 16);
    rsum += __shfl_xor(rsum, 32);
    l_i = l_i * alpha + rsum;
    m_i = mnew;
    #pragma unroll
    for (int mt = 0; mt < 3; mt++)
      #pragma unroll
      for (int r = 0; r < 4; r++) Of[mt][r] *= alpha;

    #pragma unroll
    for (int mt = 0; mt < 4; mt++) {
      uint2 pk;
      pk.x = pack2(Sf[mt][0], Sf[mt][1]);
      pk.y = pack2(Sf[mt][2], Sf[mt][3]);
      *(uint2*)&PsT[w][l16][mt*16 + 4*g] = pk;
    }
    __syncthreads();

    #pragma unroll
    for (int ks = 0; ks < 2; ks++) {
      short8v pb = *(const short8v*)&PsT[w][l16][ks*32 + g*8];
      #pragma unroll
      for (int mt = 0; mt < 3; mt++) {
        short8v va = *(const short8v*)&Vt[mt*16 + l16][ks*32 + g*8];
        Of[mt] = __builtin_amdgcn_mfma_f32_16x16x32_bf16(va, pb, Of[mt], 0, 0, 0);
      }
    }
  }

  float inv = 1.f / l_i;
  u16* orow = O + (size_t)(q0 + w*16 + l16)*320 + h*40;
  #pragma unroll
  for (int mt = 0; mt < 3; mt++) {
    #pragma unroll
    for (int rp = 0; rp < 2; rp++) {
      int d = mt*16 + 4*g + rp*2;
      if (d < 40)
        *(unsigned*)&orow[d] = pack2(Of[mt][rp*2] * inv, Of[mt][rp*2+1] * inv);
    }
  }
}

// ---------------- Cross-attention: one thread per (s, head), 77 keys, bf16 I/O ----------------
__global__ __launch_bounds__(256) void cross_attn_kernel(
    const u16* __restrict__ Q, const u16* __restrict__ Kc,
    const u16* __restrict__ Vc, u16* __restrict__ O) {
  int gid = blockIdx.x * 256 + threadIdx.x;
  int h = gid & 7;
  int s = gid >> 3;
  const u16* qp = Q + (size_t)s*320 + h*40;
  float qr[40];
  #pragma unroll
  for (int d = 0; d < 40; d++) qr[d] = bfu2f(qp[d]) * SCALE_ATTN;
  float m = -3.0e38f, l = 0.f, acc[40];
  #pragma unroll
  for (int d = 0; d < 40; d++) acc[d] = 0.f;
  for (int t = 0; t < 77; t++) {
    const u16* kp = Kc + (size_t)t*320 + h*40;
    float x = 0.f;
    #pragma unroll
    for (int d = 0; d < 40; d++) x = fmaf(qr[d], bfu2f(kp[d]), x);
    float mn = fmaxf(m, x);
    float al = __expf(m - mn);
    float p = __expf(x - mn);
    m = mn;
    l = l*al + p;
    const u16* vp = Vc + (size_t)t*320 + h*40;
    #pragma unroll
    for (int d = 0; d < 40; d++) acc[d] = acc[d]*al + p*bfu2f(vp[d]);
  }
  float inv = 1.f/l;
  u16* op = O + (size_t)s*320 + h*40;
  #pragma unroll
  for (int d = 0; d < 40; d += 2)
    *(unsigned*)&op[d] = pack2(acc[d]*inv, acc[d+1]*inv);
}

extern "C" void kernel_launch(void* const* d_in, const int* in_sizes, int n_in,
                              void* d_out, int out_size, void* d_ws, size_t ws_size,
                              hipStream_t stream) {
  const float* x        = (const float*)d_in[0];
  const float* ctx      = (const float*)d_in[1];
  const float* gn_s     = (const float*)d_in[2];
  const float* gn_b     = (const float*)d_in[3];
  const float* w_pin    = (const float*)d_in[4];
  const float* b_pin    = (const float*)d_in[5];
  const float* ln1_s    = (const float*)d_in[6];
  const float* ln1_b    = (const float*)d_in[7];
  const float* wq1      = (const float*)d_in[8];
  const float* wk1      = (const float*)d_in[9];
  const float* wv1      = (const float*)d_in[10];
  const float* wo1      = (const float*)d_in[11];
  const float* bo1      = (const float*)d_in[12];
  const float* ln2_s    = (const float*)d_in[13];
  const float* ln2_b    = (const float*)d_in[14];
  const float* wq2      = (const float*)d_in[15];
  const float* wk2      = (const float*)d_in[16];
  const float* wv2      = (const float*)d_in[17];
  const float* wo2      = (const float*)d_in[18];
  const float* bo2      = (const float*)d_in[19];
  const float* ln3_s    = (const float*)d_in[20];
  const float* ln3_b    = (const float*)d_in[21];
  const float* w_ff1    = (const float*)d_in[22];
  const float* b_ff1    = (const float*)d_in[23];
  const float* w_ff2    = (const float*)d_in[24];
  const float* b_ff2    = (const float*)d_in[25];
  const float* w_pout   = (const float*)d_in[26];
  const float* b_pout   = (const float*)d_in[27];
  float* out = (float*)d_out;

  u16* ws = (u16*)d_ws;
  const size_t HB = 4096u*320u;
  u16* h   = ws;
  u16* hn  = ws + HB;
  u16* q   = ws + 2*HB;
  u16* k   = ws + 3*HB;
  u16* v   = ws + 4*HB;
  u16* ao  = ws + 5*HB;
  u16* gnT = k;          // gnT dead before k written
  u16* gg  = q;          // GEGLU out overlays q,k,v,ao (4*HB = 4096*1280)
  u16* wb  = ws + 6*HB;
  size_t o = 0;
  u16* ctxb   = wb + o; o += 59136;
  u16* wq1T   = wb + o; o += 102400;
  u16* wk1T   = wb + o; o += 102400;
  u16* wv1T   = wb + o; o += 102400;
  u16* wo1T   = wb + o; o += 102400;
  u16* wq2T   = wb + o; o += 102400;
  u16* wk2T   = wb + o; o += 245760;
  u16* wv2T   = wb + o; o += 245760;
  u16* wo2T   = wb + o; o += 102400;
  u16* wff1T  = wb + o; o += 819200;
  u16* wff2T  = wb + o; o += 409600;
  u16* wpoutT = wb + o; o += 102400;
  u16* wpinT  = wb + o; o += 102400;
  u16* kc     = wb + o; o += 24640;
  u16* vc     = wb + o; o += 24640;
  float* chscale = (float*)(wb + o);
  float* chshift = chscale + 320;

  // weight transpose+convert pack
  TPack tp;
  const float* srcs[12] = {wq1, wk1, wv1, wo1, wq2, wo2, w_pin, w_pout, wk2, wv2, w_ff1, w_ff2};
  u16* dsts[12]         = {wq1T, wk1T, wv1T, wo1T, wq2T, wo2T, wpinT, wpoutT, wk2T, wv2T, wff1T, wff2T};
  int Ks[12] = {320,320,320,320,320,320,320,320,768,768,320,1280};
  int Ns[12] = {320,320,320,320,320,320,320,320,320,320,2560,320};
  int off = 0;
  for (int i = 0; i < 12; i++) {
    tp.d[i].src = srcs[i]; tp.d[i].dst = dsts[i];
    tp.d[i].K = Ks[i]; tp.d[i].N = Ns[i];
    tp.d[i].off = off; tp.d[i].tx = Ns[i]/32;
    off += (Ks[i]/32)*(Ns[i]/32);
  }

  dim3 blk(256), g64x5(64, 5);
  const u16* nres = nullptr;
  const float* nb = nullptr;

  hipLaunchKernelGGL(tcvt_kernel, dim3(off), blk, 0, stream, tp);
  hipLaunchKernelGGL(ctx_cvt_kernel, dim3(58), blk, 0, stream, ctx, ctxb);
  hipLaunchKernelGGL(gn_stats_kernel, dim3(32), blk, 0, stream, x, gn_s, gn_b, chscale, chshift);
  hipLaunchKernelGGL(gn_apply_t_kernel, g64x5, blk, 0, stream, x, chscale, chshift, gnT);
  // proj_in: h = gnT @ w_pin + b_pin
  hipLaunchKernelGGL((mgemm<0>), g64x5, blk, 0, stream, gnT, wpinT, b_pin, nres, nb, (void*)h, 4096, 320, 320);
  hipLaunchKernelGGL(layernorm_kernel, dim3(4096), dim3(64), 0, stream, h, ln1_s, ln1_b, hn);
  hipLaunchKernelGGL((mgemm<0>), g64x5, blk, 0, stream, hn, wq1T, nb, nres, nb, (void*)q, 4096, 320, 320);
  hipLaunchKernelGGL((mgemm<0>), g64x5, blk, 0, stream, hn, wk1T, nb, nres, nb, (void*)k, 4096, 320, 320);
  hipLaunchKernelGGL((mgemm<0>), g64x5, blk, 0, stream, hn, wv1T, nb, nres, nb, (void*)v, 4096, 320, 320);
  hipLaunchKernelGGL(self_attn_mfma, dim3(64, 8), blk, 0, stream, q, k, v, ao);
  hipLaunchKernelGGL((mgemm<0>), g64x5, blk, 0, stream, ao, wo1T, bo1, h, nb, (void*)h, 4096, 320, 320);
  hipLaunchKernelGGL(layernorm_kernel, dim3(4096), dim3(64), 0, stream, h, ln2_s, ln2_b, hn);
  hipLaunchKernelGGL((mgemm<0>), g64x5, blk, 0, stream, hn, wq2T, nb, nres, nb, (void*)q, 4096, 320, 320);
  hipLaunchKernelGGL((mgemm<0>), dim3(2, 5), blk, 0, stream, ctxb, wk2T, nb, nres, nb, (void*)kc, 77, 320, 768);
  hipLaunchKernelGGL((mgemm<0>), dim3(2, 5), blk, 0, stream, ctxb, wv2T, nb, nres, nb, (void*)vc, 77, 320, 768);
  hipLaunchKernelGGL(cross_attn_kernel, dim3(128), blk, 0, stream, q, kc, vc, ao);
  hipLaunchKernelGGL((mgemm<0>), g64x5, blk, 0, stream, ao, wo2T, bo2, h, nb, (void*)h, 4096, 320, 320);
  hipLaunchKernelGGL(layernorm_kernel, dim3(4096), dim3(64), 0, stream, h, ln3_s, ln3_b, hn);
  hipLaunchKernelGGL(geglu_mfma, dim3(64, 20), blk, 0, stream, hn, wff1T, b_ff1, gg);
  hipLaunchKernelGGL((mgemm<0>), g64x5, blk, 0, stream, gg, wff2T, b_ff2, h, nb, (void*)h, 4096, 320, 1280);
  // proj_out: out[d][s] = h @ w_pout + b_pout + x
  hipLaunchKernelGGL((mgemm<2>), g64x5, blk, 0, stream, h, wpoutT, b_pout, nres, x, (void*)out, 4096, 320, 320);
}

// Round 5
// 417.455 us; speedup vs baseline: 6.2426x; 1.4949x over previous
//
#include <hip/hip_runtime.h>
#include <math.h>

#define SCALE_ATTN 0.15811388300841897f

typedef __attribute__((ext_vector_type(8))) short short8v;
typedef __attribute__((ext_vector_type(4))) float float4v;
typedef unsigned short u16;

__device__ __forceinline__ u16 f2bf(float x) {
  unsigned u = __float_as_uint(x);
  unsigned r = (u + 0x7FFFu + ((u >> 16) & 1u)) >> 16;
  return (u16)r;
}
__device__ __forceinline__ unsigned pack2(float a, float b) {
  return (unsigned)f2bf(a) | ((unsigned)f2bf(b) << 16);
}
__device__ __forceinline__ float bfu2f(u16 u) {
  return __uint_as_float(((unsigned)u) << 16);
}

// ---------------- weight transpose+convert: W[K,N] fp32 -> WT[N,K] bf16 ----------------
struct TDesc { const float* src; u16* dst; int K, N, off, tx; };
struct TPack { TDesc d[12]; };

__global__ __launch_bounds__(256) void tcvt_kernel(TPack p) {
  __shared__ float ls[32][33];
  int bt = blockIdx.x, t = threadIdx.x;
  int ti = 0;
  #pragma unroll
  for (int i = 1; i < 12; i++) if (bt >= p.d[i].off) ti = i;
  TDesc dd = p.d[ti];
  int local = bt - dd.off;
  int n0 = (local % dd.tx) * 32, k0 = (local / dd.tx) * 32;
  #pragma unroll
  for (int i = 0; i < 4; i++) {
    int idx = t + i*256, r = idx >> 5, c = idx & 31;
    ls[r][c] = dd.src[(size_t)(k0 + r)*dd.N + n0 + c];
  }
  __syncthreads();
  #pragma unroll
  for (int i = 0; i < 2; i++) {
    int p2 = t + i*256, n = p2 >> 4, kp = (p2 & 15)*2;
    *(unsigned*)&dd.dst[(size_t)(n0 + n)*dd.K + k0 + kp] = pack2(ls[kp][n], ls[kp+1][n]);
  }
}

// ---------------- ctx fp32 -> bf16 (77*768 = 59136) ----------------
__global__ __launch_bounds__(256) void ctx_cvt_kernel(const float* __restrict__ src, u16* __restrict__ dst) {
  int idx = (blockIdx.x*256 + threadIdx.x)*4;
  if (idx < 59136) {
    float4 v = *(const float4*)&src[idx];
    uint2 o; o.x = pack2(v.x, v.y); o.y = pack2(v.z, v.w);
    *(uint2*)&dst[idx] = o;
  }
}

// ---------------- GroupNorm stats -> per-channel scale/shift ----------------
__global__ __launch_bounds__(256) void gn_stats_kernel(
    const float* __restrict__ x, const float* __restrict__ gs,
    const float* __restrict__ gb, float* __restrict__ chscale, float* __restrict__ chshift) {
  int g = blockIdx.x, tid = threadIdx.x;
  size_t base = (size_t)g * 40960;
  float sum = 0.f, sq = 0.f;
  for (int e = tid; e < 40960; e += 256) {
    float v = x[base + e];
    sum += v; sq += v * v;
  }
  __shared__ float s1[256], s2[256];
  s1[tid] = sum; s2[tid] = sq; __syncthreads();
  for (int st = 128; st > 0; st >>= 1) {
    if (tid < st) { s1[tid] += s1[tid+st]; s2[tid] += s2[tid+st]; }
    __syncthreads();
  }
  float mu = s1[0] * (1.f/40960.f);
  float var = s2[0] * (1.f/40960.f) - mu*mu;
  float rs = rsqrtf(var + 1e-6f);
  if (tid < 10) {
    int c = g*10 + tid;
    float sc = rs * gs[c];
    chscale[c] = sc;
    chshift[c] = gb[c] - mu * sc;
  }
}

// ---------------- GN apply + transpose: x[c][s] fp32 -> gnT[s][c] bf16 ----------------
__global__ __launch_bounds__(256) void gn_apply_t_kernel(
    const float* __restrict__ x, const float* __restrict__ chscale,
    const float* __restrict__ chshift, u16* __restrict__ gnT) {
  __shared__ float ts[64][65];
  __shared__ float scl[64], sft[64];
  int s0 = blockIdx.x * 64, c0 = blockIdx.y * 64;
  int t = threadIdx.x;
  if (t < 64) { scl[t] = chscale[c0 + t]; sft[t] = chshift[c0 + t]; }
  int crow = t >> 2, sch = (t & 3) * 16;
  #pragma unroll
  for (int j = 0; j < 4; j++) {
    float4 v = *(const float4*)&x[(size_t)(c0 + crow)*4096 + s0 + sch + 4*j];
    ts[crow][sch + 4*j + 0] = v.x; ts[crow][sch + 4*j + 1] = v.y;
    ts[crow][sch + 4*j + 2] = v.z; ts[crow][sch + 4*j + 3] = v.w;
  }
  __syncthreads();
  int srow = t >> 2, cch = (t & 3) * 16;
  #pragma unroll
  for (int p = 0; p < 8; p++) {
    int cl = cch + 2*p;
    float f0 = ts[cl][srow] * scl[cl] + sft[cl];
    float f1 = ts[cl+1][srow] * scl[cl+1] + sft[cl+1];
    *(unsigned*)&gnT[(size_t)(s0 + srow)*320 + c0 + cl] = pack2(f0, f1);
  }
}

// ---------------- LayerNorm bf16->bf16: one wave per row of 320 ----------------
__global__ __launch_bounds__(64) void layernorm_kernel(
    const u16* __restrict__ X, const float* __restrict__ s,
    const float* __restrict__ b, u16* __restrict__ Y) {
  int row = blockIdx.x, t = threadIdx.x;
  const u16* xr = X + (size_t)row*320;
  float v[5], sum = 0.f, sq = 0.f;
  #pragma unroll
  for (int i = 0; i < 5; i++) { v[i] = bfu2f(xr[t + 64*i]); sum += v[i]; sq += v[i]*v[i]; }
  #pragma unroll
  for (int o = 32; o > 0; o >>= 1) { sum += __shfl_down(sum, o); sq += __shfl_down(sq, o); }
  sum = __shfl(sum, 0); sq = __shfl(sq, 0);
  float mu = sum * (1.f/320.f);
  float var = sq * (1.f/320.f) - mu*mu;
  float rs = rsqrtf(var + 1e-5f);
  u16* yr = Y + (size_t)row*320;
  #pragma unroll
  for (int i = 0; i < 5; i++) {
    int c = t + 64*i;
    yr[c] = f2bf((v[i]-mu)*rs*s[c] + b[c]);
  }
}

// ---------------- MFMA GEMM: C[M,N] = A[M,K](bf16) * BT[N,K](bf16)^T ----------------
// MODE 0: bf16 out C[m*N+n], optional fp32 bias[n], optional bf16 res
// MODE 1: bf16 out segmented: col = bn+nn, seg = col/320, write Cout + seg*segStride + m*320 + col%320
// MODE 2: proj_out: fp32 out[n*4096+m] = acc + bias[n] + xres[n*4096+m]
template<int MODE>
__global__ __launch_bounds__(256) void mgemm(
    const u16* __restrict__ A, const u16* __restrict__ BT,
    const float* __restrict__ bias, const u16* __restrict__ res,
    const float* __restrict__ xres, void* __restrict__ Cout,
    int M, int N, int K, int segStride) {
  __shared__ __align__(16) u16 smem[2*64*72];
  u16* As = smem;
  u16* Bs = smem + 64*72;
  const int t = threadIdx.x;
  const int lane = t & 63, w = t >> 6, l16 = lane & 15, g = lane >> 4;
  const int bm = blockIdx.x * 64, bn = blockIdx.y * 64;
  const int m0 = (w & 1) * 32, n0 = (w >> 1) * 32;
  float4v acc[2][2] = {};
  const int ar = t >> 2, ac = (t & 3) * 16;
  const bool aok = (bm + ar) < M;

  for (int k0 = 0; k0 < K; k0 += 64) {
    __syncthreads();
    short8v a0 = {}, a1 = {};
    if (aok) {
      const u16* ga = &A[(size_t)(bm + ar)*K + k0 + ac];
      a0 = *(const short8v*)ga; a1 = *(const short8v*)(ga + 8);
    }
    *(short8v*)&As[ar*72 + ac] = a0;
    *(short8v*)&As[ar*72 + ac + 8] = a1;
    const u16* gbp = &BT[(size_t)(bn + ar)*K + k0 + ac];
    *(short8v*)&Bs[ar*72 + ac] = *(const short8v*)gbp;
    *(short8v*)&Bs[ar*72 + ac + 8] = *(const short8v*)(gbp + 8);
    __syncthreads();
    #pragma unroll
    for (int ks = 0; ks < 2; ks++) {
      short8v af[2], bfv[2];
      #pragma unroll
      for (int mt = 0; mt < 2; mt++)
        af[mt] = *(const short8v*)&As[(m0 + 16*mt + l16)*72 + ks*32 + g*8];
      #pragma unroll
      for (int nt = 0; nt < 2; nt++)
        bfv[nt] = *(const short8v*)&Bs[(n0 + 16*nt + l16)*72 + ks*32 + g*8];
      #pragma unroll
      for (int mt = 0; mt < 2; mt++)
        #pragma unroll
        for (int nt = 0; nt < 2; nt++)
          acc[mt][nt] = __builtin_amdgcn_mfma_f32_16x16x32_bf16(af[mt], bfv[nt], acc[mt][nt], 0, 0, 0);
    }
  }
  __syncthreads();
  float* Cs = (float*)smem;  // [64][68]
  #pragma unroll
  for (int mt = 0; mt < 2; mt++)
    #pragma unroll
    for (int nt = 0; nt < 2; nt++)
      #pragma unroll
      for (int r = 0; r < 4; r++)
        Cs[(m0 + 16*mt + 4*g + r)*68 + n0 + 16*nt + l16] = acc[mt][nt][r];
  __syncthreads();

  if (MODE == 0) {
    u16* C = (u16*)Cout;
    #pragma unroll
    for (int i = 0; i < 8; i++) {
      int p = t + i*256;
      int mm = p >> 5, nn = (p & 31)*2;
      int gm = bm + mm;
      if (gm >= M) continue;
      float f0 = Cs[mm*68 + nn], f1 = Cs[mm*68 + nn + 1];
      if (bias) { f0 += bias[bn + nn]; f1 += bias[bn + nn + 1]; }
      if (res) {
        unsigned u = *(const unsigned*)&res[(size_t)gm*N + bn + nn];
        f0 += bfu2f((u16)(u & 0xffffu));
        f1 += bfu2f((u16)(u >> 16));
      }
      *(unsigned*)&C[(size_t)gm*N + bn + nn] = pack2(f0, f1);
    }
  } else if (MODE == 1) {
    u16* C = (u16*)Cout + (size_t)(bn / 320) * segStride;
    int nb = bn % 320;
    #pragma unroll
    for (int i = 0; i < 8; i++) {
      int p = t + i*256;
      int mm = p >> 5, nn = (p & 31)*2;
      int gm = bm + mm;
      if (gm >= M) continue;
      *(unsigned*)&C[(size_t)gm*320 + nb + nn] = pack2(Cs[mm*68 + nn], Cs[mm*68 + nn + 1]);
    }
  } else {
    float* C = (float*)Cout;
    int nloc = t >> 2, mch = (t & 3) * 16;
    float bb = bias[bn + nloc];
    #pragma unroll
    for (int j = 0; j < 4; j++) {
      int m4 = mch + j*4;
      float4 xv = *(const float4*)&xres[(size_t)(bn + nloc)*4096 + bm + m4];
      float4 ov;
      ov.x = Cs[(m4+0)*68 + nloc] + bb + xv.x;
      ov.y = Cs[(m4+1)*68 + nloc] + bb + xv.y;
      ov.z = Cs[(m4+2)*68 + nloc] + bb + xv.z;
      ov.w = Cs[(m4+3)*68 + nloc] + bb + xv.w;
      *(float4*)&C[(size_t)(bn + nloc)*4096 + bm + m4] = ov;
    }
  }
}

// ---------------- GEGLU MFMA ----------------
__global__ __launch_bounds__(256) void geglu_mfma(
    const u16* __restrict__ A, const u16* __restrict__ BT,
    const float* __restrict__ bias, u16* __restrict__ C) {
  __shared__ __align__(16) u16 smem[3*64*72];
  u16* As = smem;
  u16* Ba = smem + 64*72;
  u16* Bg = smem + 2*64*72;
  const int t = threadIdx.x;
  const int lane = t & 63, w = t >> 6, l16 = lane & 15, g = lane >> 4;
  const int bm = blockIdx.x * 64, bn = blockIdx.y * 64;
  const int m0 = (w & 1) * 32, n0 = (w >> 1) * 32;
  float4v aacc[2][2] = {}, gacc[2][2] = {};
  const int ar = t >> 2, ac = (t & 3) * 16;

  for (int k0 = 0; k0 < 320; k0 += 64) {
    __syncthreads();
    {
      const u16* ga = &A[(size_t)(bm + ar)*320 + k0 + ac];
      *(short8v*)&As[ar*72 + ac] = *(const short8v*)ga;
      *(short8v*)&As[ar*72 + ac + 8] = *(const short8v*)(ga + 8);
      const u16* gba = &BT[(size_t)(bn + ar)*320 + k0 + ac];
      *(short8v*)&Ba[ar*72 + ac] = *(const short8v*)gba;
      *(short8v*)&Ba[ar*72 + ac + 8] = *(const short8v*)(gba + 8);
      const u16* gbg = &BT[(size_t)(1280 + bn + ar)*320 + k0 + ac];
      *(short8v*)&Bg[ar*72 + ac] = *(const short8v*)gbg;
      *(short8v*)&Bg[ar*72 + ac + 8] = *(const short8v*)(gbg + 8);
    }
    __syncthreads();
    #pragma unroll
    for (int ks = 0; ks < 2; ks++) {
      short8v af[2], bav[2], bgv[2];
      #pragma unroll
      for (int mt = 0; mt < 2; mt++)
        af[mt] = *(const short8v*)&As[(m0 + 16*mt + l16)*72 + ks*32 + g*8];
      #pragma unroll
      for (int nt = 0; nt < 2; nt++) {
        bav[nt] = *(const short8v*)&Ba[(n0 + 16*nt + l16)*72 + ks*32 + g*8];
        bgv[nt] = *(const short8v*)&Bg[(n0 + 16*nt + l16)*72 + ks*32 + g*8];
      }
      #pragma unroll
      for (int mt = 0; mt < 2; mt++)
        #pragma unroll
        for (int nt = 0; nt < 2; nt++) {
          aacc[mt][nt] = __builtin_amdgcn_mfma_f32_16x16x32_bf16(af[mt], bav[nt], aacc[mt][nt], 0, 0, 0);
          gacc[mt][nt] = __builtin_amdgcn_mfma_f32_16x16x32_bf16(af[mt], bgv[nt], gacc[mt][nt], 0, 0, 0);
        }
    }
  }
  __syncthreads();
  float* Cs = (float*)smem;
  #pragma unroll
  for (int nt = 0; nt < 2; nt++) {
    int col = n0 + 16*nt + l16;
    float ba = bias[bn + col];
    float bg2 = bias[1280 + bn + col];
    #pragma unroll
    for (int mt = 0; mt < 2; mt++)
      #pragma unroll
      for (int r = 0; r < 4; r++) {
        float a = aacc[mt][nt][r] + ba;
        float gv = gacc[mt][nt][r] + bg2;
        float gl = 0.5f * gv * (1.f + erff(gv * 0.70710678118654752f));
        Cs[(m0 + 16*mt + 4*g + r)*68 + col] = a * gl;
      }
  }
  __syncthreads();
  #pragma unroll
  for (int i = 0; i < 8; i++) {
    int p = t + i*256;
    int mm = p >> 5, nn = (p & 31)*2;
    *(unsigned*)&C[(size_t)(bm + mm)*1280 + bn + nn] = pack2(Cs[mm*68 + nn], Cs[mm*68 + nn + 1]);
  }
}

// ---------------- Self-attention partial: K-split flash MFMA ----------------
// Grid (64 qtiles, 8 heads, 4 splits). Each block: 64 queries x 1024 keys.
// Emits unnormalized O^T partial (fp32) + per-query m,l.
__global__ __launch_bounds__(256) void self_attn_part(
    const u16* __restrict__ Q, const u16* __restrict__ K,
    const u16* __restrict__ V, float* __restrict__ Opart,
    float* __restrict__ Mp, float* __restrict__ Lp) {
  const int h = blockIdx.y;
  const int q0 = blockIdx.x * 64;
  const int sp = blockIdx.z;
  const int tid = threadIdx.x;
  const int w = tid >> 6, lane = tid & 63;
  const int l16 = lane & 15, g = lane >> 4;

  __shared__ __align__(16) u16 Kls[64][72];
  __shared__ __align__(16) u16 Vt[48][72];
  __shared__ __align__(16) u16 PsT[4][16][72];

  for (int e = tid; e < 64*12; e += 256) {
    int r = e / 12, c = e % 12;
    *(unsigned*)&Kls[r][40 + 2*c] = 0u;
  }
  for (int e = tid; e < 8*32; e += 256) {
    int r = 40 + (e >> 5), c = e & 31;
    *(unsigned*)&Vt[r][2*c] = 0u;
  }

  short8v Qb[2];
  {
    const u16* qrow = Q + (size_t)(q0 + w*16 + l16)*320 + h*40;
    Qb[0] = *(const short8v*)(qrow + g*8);
    short8v z = {};
    Qb[1] = (g == 0) ? *(const short8v*)(qrow + 32) : z;
  }

  float m_i = -1e30f, l_i = 0.f;
  float4v Of[3] = {};

  const int ktEnd = sp*1024 + 1024;
  for (int kt = sp*1024; kt < ktEnd; kt += 64) {
    __syncthreads();
    for (int e = tid; e < 1280; e += 256) {
      int key = e / 20, dp = e % 20;
      *(unsigned*)&Kls[key][dp*2] =
        *(const unsigned*)&K[(size_t)(kt + key)*320 + h*40 + dp*2];
    }
    for (int e = tid; e < 1280; e += 256) {
      int kp = e / 40, d = e % 40;
      unsigned u0 = V[(size_t)(kt + kp*2    )*320 + h*40 + d];
      unsigned u1 = V[(size_t)(kt + kp*2 + 1)*320 + h*40 + d];
      *(unsigned*)&Vt[d][kp*2] = u0 | (u1 << 16);
    }
    __syncthreads();

    float4v Sf[4];
    #pragma unroll
    for (int mt = 0; mt < 4; mt++) {
      short8v ka0 = *(const short8v*)&Kls[mt*16 + l16][g*8];
      short8v ka1 = *(const short8v*)&Kls[mt*16 + l16][32 + g*8];
      float4v s = {};
      s = __builtin_amdgcn_mfma_f32_16x16x32_bf16(ka0, Qb[0], s, 0, 0, 0);
      s = __builtin_amdgcn_mfma_f32_16x16x32_bf16(ka1, Qb[1], s, 0, 0, 0);
      Sf[mt] = s;
    }

    float mx = -1e30f;
    #pragma unroll
    for (int mt = 0; mt < 4; mt++)
      #pragma unroll
      for (int r = 0; r < 4; r++) mx = fmaxf(mx, Sf[mt][r]);
    mx = fmaxf(mx, __shfl_xor(mx, 16));
    mx = fmaxf(mx, __shfl_xor(mx, 32));
    float mnew = fmaxf(m_i, mx);
    float alpha = __expf((m_i - mnew) * SCALE_ATTN);
    float rsum = 0.f;
    #pragma unroll
    for (int mt = 0; mt < 4; mt++)
      #pragma unroll
      for (int r = 0; r < 4; r++) {
        float p = __expf((Sf[mt][r] - mnew) * SCALE_ATTN);
        Sf[mt][r] = p; rsum += p;
      }
    rsum += __shfl_xor(rsum, 16);
    rsum += __shfl_xor(rsum, 32);
    l_i = l_i * alpha + rsum;
    m_i = mnew;
    #pragma unroll
    for (int mt = 0; mt < 3; mt++)
      #pragma unroll
      for (int r = 0; r < 4; r++) Of[mt][r] *= alpha;

    #pragma unroll
    for (int mt = 0; mt < 4; mt++) {
      uint2 pk;
      pk.x = pack2(Sf[mt][0], Sf[mt][1]);
      pk.y = pack2(Sf[mt][2], Sf[mt][3]);
      *(uint2*)&PsT[w][l16][mt*16 + 4*g] = pk;
    }
    __syncthreads();

    #pragma unroll
    for (int ks = 0; ks < 2; ks++) {
      short8v pb = *(const short8v*)&PsT[w][l16][ks*32 + g*8];
      #pragma unroll
      for (int mt = 0; mt < 3; mt++) {
        short8v va = *(const short8v*)&Vt[mt*16 + l16][ks*32 + g*8];
        Of[mt] = __builtin_amdgcn_mfma_f32_16x16x32_bf16(va, pb, Of[mt], 0, 0, 0);
      }
    }
  }

  // store unnormalized partial O^T + m,l
  const int q = q0 + w*16 + l16;
  float* orow = Opart + (size_t)sp*4096*320 + (size_t)q*320 + h*40;
  #pragma unroll
  for (int mt = 0; mt < 3; mt++) {
    #pragma unroll
    for (int rp = 0; rp < 2; rp++) {
      int d = mt*16 + 4*g + rp*2;
      if (d < 40) {
        float2 val = { Of[mt][rp*2], Of[mt][rp*2+1] };
        *(float2*)&orow[d] = val;
      }
    }
  }
  if (g == 0) {
    Mp[sp*32768 + q*8 + h] = m_i;
    Lp[sp*32768 + q*8 + h] = l_i;
  }
}

// ---------------- merge 4 partials -> ao bf16 ----------------
__global__ __launch_bounds__(256) void attn_merge(
    const float* __restrict__ Opart, const float* __restrict__ Mp,
    const float* __restrict__ Lp, u16* __restrict__ O) {
  int gid = blockIdx.x*256 + threadIdx.x;   // < 4096*8*20
  int dp = gid % 20;
  int qh = gid / 20;
  int q = qh >> 3, h = qh & 7;
  float m0 = Mp[qh], m1 = Mp[32768 + qh], m2 = Mp[2*32768 + qh], m3 = Mp[3*32768 + qh];
  float ms = fmaxf(fmaxf(m0, m1), fmaxf(m2, m3));
  float w0 = __expf((m0 - ms) * SCALE_ATTN);
  float w1 = __expf((m1 - ms) * SCALE_ATTN);
  float w2 = __expf((m2 - ms) * SCALE_ATTN);
  float w3 = __expf((m3 - ms) * SCALE_ATTN);
  float ls = Lp[qh]*w0 + Lp[32768 + qh]*w1 + Lp[2*32768 + qh]*w2 + Lp[3*32768 + qh]*w3;
  size_t base = (size_t)q*320 + h*40 + dp*2;
  const size_t HBf = 4096u*320u;
  float2 o0 = *(const float2*)&Opart[base];
  float2 o1 = *(const float2*)&Opart[HBf + base];
  float2 o2 = *(const float2*)&Opart[2*HBf + base];
  float2 o3 = *(const float2*)&Opart[3*HBf + base];
  float inv = 1.f / ls;
  float r0 = (o0.x*w0 + o1.x*w1 + o2.x*w2 + o3.x*w3) * inv;
  float r1 = (o0.y*w0 + o1.y*w1 + o2.y*w2 + o3.y*w3) * inv;
  *(unsigned*)&O[base] = pack2(r0, r1);
}

// ---------------- Cross-attention: single-shot MFMA, 77 keys (pad 80/96) ----------------
__global__ __launch_bounds__(256) void cross_attn_mfma(
    const u16* __restrict__ Q, const u16* __restrict__ Kc,
    const u16* __restrict__ Vc, u16* __restrict__ O) {
  const int h = blockIdx.y;
  const int q0 = blockIdx.x * 64;
  const int tid = threadIdx.x;
  const int w = tid >> 6, lane = tid & 63;
  const int l16 = lane & 15, g = lane >> 4;

  __shared__ __align__(16) u16 Kls[80][72];
  __shared__ __align__(16) u16 Vt[48][104];
  __shared__ __align__(16) u16 PsT[4][16][104];

  // zero pads
  for (int e = tid; e < 80*12; e += 256) {           // Kls cols 40..63
    int r = e / 12, c = e % 12;
    *(unsigned*)&Kls[r][40 + 2*c] = 0u;
  }
  for (int e = tid; e < 48*52; e += 256) {           // whole Vt
    int r = e / 52, c = e % 52;
    *(unsigned*)&Vt[r][2*c] = 0u;
  }
  {                                                   // PsT cols 80..95 per wave
    int r = lane >> 2, c4 = (lane & 3)*4;
    uint2 z; z.x = 0u; z.y = 0u;
    *(uint2*)&PsT[w][r][80 + c4] = z;
  }

  short8v Qb[2];
  {
    const u16* qrow = Q + (size_t)(q0 + w*16 + l16)*320 + h*40;
    Qb[0] = *(const short8v*)(qrow + g*8);
    short8v z = {};
    Qb[1] = (g == 0) ? *(const short8v*)(qrow + 32) : z;
  }

  // stage K (80 keys, zeros beyond 76)
  for (int e = tid; e < 1600; e += 256) {
    int key = e / 20, dp = e % 20;
    unsigned val = 0u;
    if (key < 77) val = *(const unsigned*)&Kc[(size_t)key*320 + h*40 + dp*2];
    *(unsigned*)&Kls[key][dp*2] = val;
  }
  __syncthreads();
  // stage V transposed (after barrier so Vt zero-fill is complete)
  for (int e = tid; e < 1600; e += 256) {
    int kp = e / 40, d = e % 40;
    unsigned u0 = (kp*2     < 77) ? (unsigned)Vc[(size_t)(kp*2    )*320 + h*40 + d] : 0u;
    unsigned u1 = (kp*2 + 1 < 77) ? (unsigned)Vc[(size_t)(kp*2 + 1)*320 + h*40 + d] : 0u;
    *(unsigned*)&Vt[d][kp*2] = u0 | (u1 << 16);
  }
  __syncthreads();

  // S^T = K·Q^T over 80 keys
  float4v Sf[5];
  #pragma unroll
  for (int mt = 0; mt < 5; mt++) {
    short8v ka0 = *(const short8v*)&Kls[mt*16 + l16][g*8];
    short8v ka1 = *(const short8v*)&Kls[mt*16 + l16][32 + g*8];
    float4v s = {};
    s = __builtin_amdgcn_mfma_f32_16x16x32_bf16(ka0, Qb[0], s, 0, 0, 0);
    s = __builtin_amdgcn_mfma_f32_16x16x32_bf16(ka1, Qb[1], s, 0, 0, 0);
    Sf[mt] = s;
  }

  // mask invalid keys, exact softmax (single pass)
  float mx = -1e30f;
  #pragma unroll
  for (int mt = 0; mt < 5; mt++)
    #pragma unroll
    for (int r = 0; r < 4; r++) {
      int key = mt*16 + 4*g + r;
      if (key >= 77) Sf[mt][r] = -1e30f;
      mx = fmaxf(mx, Sf[mt][r]);
    }
  mx = fmaxf(mx, __shfl_xor(mx, 16));
  mx = fmaxf(mx, __shfl_xor(mx, 32));
  float rsum = 0.f;
  #pragma unroll
  for (int mt = 0; mt < 5; mt++)
    #pragma unroll
    for (int r = 0; r < 4; r++) {
      float p = __expf((Sf[mt][r] - mx) * SCALE_ATTN);
      Sf[mt][r] = p; rsum += p;
    }
  rsum += __shfl_xor(rsum, 16);
  rsum += __shfl_xor(rsum, 32);

  #pragma unroll
  for (int mt = 0; mt < 5; mt++) {
    uint2 pk;
    pk.x = pack2(Sf[mt][0], Sf[mt][1]);
    pk.y = pack2(Sf[mt][2], Sf[mt][3]);
    *(uint2*)&PsT[w][l16][mt*16 + 4*g] = pk;
  }
  __syncthreads();

  float4v Of[3] = {};
  #pragma unroll
  for (int ks = 0; ks < 3; ks++) {
    short8v pb = *(const short8v*)&PsT[w][l16][ks*32 + g*8];
    #pragma unroll
    for (int mt = 0; mt < 3; mt++) {
      short8v va = *(const short8v*)&Vt[mt*16 + l16][ks*32 + g*8];
      Of[mt] = __builtin_amdgcn_mfma_f32_16x16x32_bf16(va, pb, Of[mt], 0, 0, 0);
    }
  }

  float inv = 1.f / rsum;
  u16* orow = O + (size_t)(q0 + w*16 + l16)*320 + h*40;
  #pragma unroll
  for (int mt = 0; mt < 3; mt++) {
    #pragma unroll
    for (int rp = 0; rp < 2; rp++) {
      int d = mt*16 + 4*g + rp*2;
      if (d < 40)
        *(unsigned*)&orow[d] = pack2(Of[mt][rp*2] * inv, Of[mt][rp*2+1] * inv);
    }
  }
}

extern "C" void kernel_launch(void* const* d_in, const int* in_sizes, int n_in,
                              void* d_out, int out_size, void* d_ws, size_t ws_size,
                              hipStream_t stream) {
  const float* x        = (const float*)d_in[0];
  const float* ctx      = (const float*)d_in[1];
  const float* gn_s     = (const float*)d_in[2];
  const float* gn_b     = (const float*)d_in[3];
  const float* w_pin    = (const float*)d_in[4];
  const float* b_pin    = (const float*)d_in[5];
  const float* ln1_s    = (const float*)d_in[6];
  const float* ln1_b    = (const float*)d_in[7];
  const float* wq1      = (const float*)d_in[8];
  const float* wk1      = (const float*)d_in[9];
  const float* wv1      = (const float*)d_in[10];
  const float* wo1      = (const float*)d_in[11];
  const float* bo1      = (const float*)d_in[12];
  const float* ln2_s    = (const float*)d_in[13];
  const float* ln2_b    = (const float*)d_in[14];
  const float* wq2      = (const float*)d_in[15];
  const float* wk2      = (const float*)d_in[16];
  const float* wv2      = (const float*)d_in[17];
  const float* wo2      = (const float*)d_in[18];
  const float* bo2      = (const float*)d_in[19];
  const float* ln3_s    = (const float*)d_in[20];
  const float* ln3_b    = (const float*)d_in[21];
  const float* w_ff1    = (const float*)d_in[22];
  const float* b_ff1    = (const float*)d_in[23];
  const float* w_ff2    = (const float*)d_in[24];
  const float* b_ff2    = (const float*)d_in[25];
  const float* w_pout   = (const float*)d_in[26];
  const float* b_pout   = (const float*)d_in[27];
  float* out = (float*)d_out;

  u16* ws = (u16*)d_ws;
  const size_t HB = 4096u*320u;
  u16* h   = ws;
  u16* hn  = ws + HB;
  u16* q   = ws + 2*HB;    // q,k,v contiguous (QKV fused epilogue relies on this)
  u16* k   = ws + 3*HB;
  u16* v   = ws + 4*HB;
  u16* ao  = ws + 5*HB;
  u16* gnT = k;
  u16* gg  = q;
  u16* wb  = ws + 6*HB;
  size_t o = 0;
  u16* ctxb   = wb + o; o += 59136;
  u16* wq1T   = wb + o; o += 102400;   // stacked: wq1T,wk1T,wv1T = [960][320]
  u16* wk1T   = wb + o; o += 102400;
  u16* wv1T   = wb + o; o += 102400;
  u16* wo1T   = wb + o; o += 102400;
  u16* wq2T   = wb + o; o += 102400;
  u16* wk2T   = wb + o; o += 245760;   // stacked: wk2T,wv2T = [640][768]
  u16* wv2T   = wb + o; o += 245760;
  u16* wo2T   = wb + o; o += 102400;
  u16* wff1T  = wb + o; o += 819200;
  u16* wff2T  = wb + o; o += 409600;
  u16* wpoutT = wb + o; o += 102400;
  u16* wpinT  = wb + o; o += 102400;
  u16* kc     = wb + o; o += 24640;    // kc,vc contiguous, segStride 24640
  u16* vc     = wb + o; o += 24640;
  float* chscale = (float*)(wb + o);
  float* chshift = chscale + 320;
  float* Opart = chshift + 320;        // 4 x 4096 x 320 fp32 = 21 MB
  float* Mpart = Opart + 4*HB;
  float* Lpart = Mpart + 4*32768;

  TPack tp;
  const float* srcs[12] = {wq1, wk1, wv1, wo1, wq2, wo2, w_pin, w_pout, wk2, wv2, w_ff1, w_ff2};
  u16* dsts[12]         = {wq1T, wk1T, wv1T, wo1T, wq2T, wo2T, wpinT, wpoutT, wk2T, wv2T, wff1T, wff2T};
  int Ks[12] = {320,320,320,320,320,320,320,320,768,768,320,1280};
  int Ns[12] = {320,320,320,320,320,320,320,320,320,320,2560,320};
  int off = 0;
  for (int i = 0; i < 12; i++) {
    tp.d[i].src = srcs[i]; tp.d[i].dst = dsts[i];
    tp.d[i].K = Ks[i]; tp.d[i].N = Ns[i];
    tp.d[i].off = off; tp.d[i].tx = Ns[i]/32;
    off += (Ks[i]/32)*(Ns[i]/32);
  }

  dim3 blk(256), g64x5(64, 5);
  const u16* nres = nullptr;
  const float* nb = nullptr;

  hipLaunchKernelGGL(tcvt_kernel, dim3(off), blk, 0, stream, tp);
  hipLaunchKernelGGL(ctx_cvt_kernel, dim3(58), blk, 0, stream, ctx, ctxb);
  hipLaunchKernelGGL(gn_stats_kernel, dim3(32), blk, 0, stream, x, gn_s, gn_b, chscale, chshift);
  hipLaunchKernelGGL(gn_apply_t_kernel, g64x5, blk, 0, stream, x, chscale, chshift, gnT);
  hipLaunchKernelGGL((mgemm<0>), g64x5, blk, 0, stream, gnT, wpinT, b_pin, nres, nb, (void*)h, 4096, 320, 320, 0);
  hipLaunchKernelGGL(layernorm_kernel, dim3(4096), dim3(64), 0, stream, h, ln1_s, ln1_b, hn);
  // fused QKV: N=960, columns route to q/k/v (contiguous, segStride HB)
  hipLaunchKernelGGL((mgemm<1>), dim3(64, 15), blk, 0, stream, hn, wq1T, nb, nres, nb, (void*)q, 4096, 960, 320, (int)HB);
  hipLaunchKernelGGL(self_attn_part, dim3(64, 8, 4), blk, 0, stream, q, k, v, Opart, Mpart, Lpart);
  hipLaunchKernelGGL(attn_merge, dim3(2560), blk, 0, stream, Opart, Mpart, Lpart, ao);
  hipLaunchKernelGGL((mgemm<0>), g64x5, blk, 0, stream, ao, wo1T, bo1, h, nb, (void*)h, 4096, 320, 320, 0);
  hipLaunchKernelGGL(layernorm_kernel, dim3(4096), dim3(64), 0, stream, h, ln2_s, ln2_b, hn);
  hipLaunchKernelGGL((mgemm<0>), g64x5, blk, 0, stream, hn, wq2T, nb, nres, nb, (void*)q, 4096, 320, 320, 0);
  // fused kc/vc: N=640, K=768
  hipLaunchKernelGGL((mgemm<1>), dim3(2, 10), blk, 0, stream, ctxb, wk2T, nb, nres, nb, (void*)kc, 77, 640, 768, 24640);
  hipLaunchKernelGGL(cross_attn_mfma, dim3(64, 8), blk, 0, stream, q, kc, vc, ao);
  hipLaunchKernelGGL((mgemm<0>), g64x5, blk, 0, stream, ao, wo2T, bo2, h, nb, (void*)h, 4096, 320, 320, 0);
  hipLaunchKernelGGL(layernorm_kernel, dim3(4096), dim3(64), 0, stream, h, ln3_s, ln3_b, hn);
  hipLaunchKernelGGL(geglu_mfma, dim3(64, 20), blk, 0, stream, hn, wff1T, b_ff1, gg);
  hipLaunchKernelGGL((mgemm<0>), g64x5, blk, 0, stream, gg, wff2T, b_ff2, h, nb, (void*)h, 4096, 320, 1280, 0);
  hipLaunchKernelGGL((mgemm<2>), g64x5, blk, 0, stream, h, wpoutT, b_pout, nres, x, (void*)out, 4096, 320, 320, 0);
}